// Round 4
// baseline (893.091 us; speedup 1.0000x reference)
//
#include <hip/hip_runtime.h>
#include <hip/hip_bf16.h>

typedef unsigned short u16;
typedef __bf16 bf16x8 __attribute__((ext_vector_type(8)));
typedef u16 u16x8 __attribute__((ext_vector_type(8)));
typedef float f32x4 __attribute__((ext_vector_type(4)));

#define S_LEN 2048
#define NH 8
#define DMODEL 512
#define TOPK 204
#define CAP 768

__device__ __forceinline__ u16 f2b(float f) {
  __hip_bfloat16 h = __float2bfloat16(f);
  return __builtin_bit_cast(u16, h);
}
__device__ __forceinline__ unsigned kmap(float f) {
  u16 b = f2b(f);
  return (unsigned)(u16)(b ^ ((b & 0x8000) ? 0xFFFFu : 0x8000u));
}
__device__ __forceinline__ float kunmap(unsigned k) {
  unsigned tb = (k & 0x8000u) ? (k ^ 0x8000u) : (~k & 0xFFFFu);
  return __uint_as_float(tb << 16);
}

// ---------------- transpose fp32 (R x C) -> bf16 (C x R) ----------------
__global__ void transpose_w(const float* __restrict__ in, u16* __restrict__ out, int R, int C) {
  __shared__ float tile[32][33];
  int c0 = blockIdx.x * 32, r0 = blockIdx.y * 32;
  int tx = threadIdx.x & 31, ty = threadIdx.x >> 5;
#pragma unroll
  for (int i = 0; i < 32; i += 8)
    tile[ty + i][tx] = in[(long long)(r0 + ty + i) * C + c0 + tx];
  __syncthreads();
#pragma unroll
  for (int i = 0; i < 32; i += 8)
    out[(long long)(c0 + ty + i) * R + r0 + tx] = f2b(tile[tx][ty + i]);
}

// 4 x (512x512) weight transposes in one launch
__global__ void transpose_w4(const float* __restrict__ W0, const float* __restrict__ W1,
                             const float* __restrict__ W2, const float* __restrict__ W3,
                             u16* __restrict__ O0, u16* __restrict__ O1,
                             u16* __restrict__ O2, u16* __restrict__ O3) {
  __shared__ float tile[32][33];
  const float* in;
  u16* out;
  switch (blockIdx.z) {
    case 0: in = W0; out = O0; break;
    case 1: in = W1; out = O1; break;
    case 2: in = W2; out = O2; break;
    default: in = W3; out = O3; break;
  }
  int c0 = blockIdx.x * 32, r0 = blockIdx.y * 32;
  int tx = threadIdx.x & 31, ty = threadIdx.x >> 5;
#pragma unroll
  for (int i = 0; i < 32; i += 8)
    tile[ty + i][tx] = in[(long long)(r0 + ty + i) * 512 + c0 + tx];
  __syncthreads();
#pragma unroll
  for (int i = 0; i < 32; i += 8)
    out[(long long)(c0 + ty + i) * 512 + r0 + tx] = f2b(tile[tx][ty + i]);
}

// ---------------- fp32 -> bf16 convert ----------------
__global__ void conv_b(const float* __restrict__ in, u16* __restrict__ out, int n) {
  int i = blockIdx.x * 256 + threadIdx.x;
  if (i < n) out[i] = f2b(in[i]);
}

// ---------------- generic bf16 GEMM: C = A(MxK) @ BT(NxK)^T * scale + bias ----------------
template <int MODE>
__global__ __launch_bounds__(256) void gemm_bt(
    const u16* __restrict__ A, const u16* __restrict__ BT, const float* __restrict__ bias,
    float* __restrict__ outF, u16* __restrict__ outB,
    int M, int N, int K, float scale) {
  __shared__ u16 As[128 * 32];
  __shared__ u16 Bs[128 * 32];
  int n0 = blockIdx.x * 128, m0 = blockIdx.y * 128;
  int t = threadIdx.x;
  int lane = t & 63, wv = t >> 6;
  int mw = (wv & 1) * 64, nw = (wv >> 1) * 64;
  int fr = lane & 15, fg = lane >> 4;
  f32x4 acc[4][4] = {};
  for (int kt = 0; kt < K; kt += 32) {
    int e0 = t * 8;
    int r0r = e0 >> 5, c0c = e0 & 31;
    int e1 = e0 + 2048;
    int r1r = e1 >> 5, c1c = e1 & 31;
    *(u16x8*)&As[e0] = *(const u16x8*)&A[(long long)(m0 + r0r) * K + kt + c0c];
    *(u16x8*)&As[e1] = *(const u16x8*)&A[(long long)(m0 + r1r) * K + kt + c1c];
    *(u16x8*)&Bs[e0] = *(const u16x8*)&BT[(long long)(n0 + r0r) * K + kt + c0c];
    *(u16x8*)&Bs[e1] = *(const u16x8*)&BT[(long long)(n0 + r1r) * K + kt + c1c];
    __syncthreads();
    bf16x8 af[4], bfv[4];
#pragma unroll
    for (int i = 0; i < 4; i++) af[i] = *(const bf16x8*)&As[(mw + i * 16 + fr) * 32 + fg * 8];
#pragma unroll
    for (int i = 0; i < 4; i++) bfv[i] = *(const bf16x8*)&Bs[(nw + i * 16 + fr) * 32 + fg * 8];
#pragma unroll
    for (int i = 0; i < 4; i++)
#pragma unroll
      for (int j = 0; j < 4; j++)
        acc[i][j] = __builtin_amdgcn_mfma_f32_16x16x32_bf16(af[i], bfv[j], acc[i][j], 0, 0, 0);
    __syncthreads();
  }
#pragma unroll
  for (int i = 0; i < 4; i++)
#pragma unroll
    for (int j = 0; j < 4; j++) {
      int mloc = mw + i * 16 + fg * 4;
      int n = n0 + nw + j * 16 + fr;
      float bvl = bias ? bias[n] : 0.f;
#pragma unroll
      for (int r = 0; r < 4; r++) {
        int m = m0 + mloc + r;
        float v = acc[i][j][r] * scale + bvl;
        if constexpr (MODE == 0) {
          outF[(long long)m * N + n] = v;
        } else if constexpr (MODE == 4) {
          outF[(long long)m * N + n] = v;
          outB[(long long)m * N + n] = f2b(v);
        } else if constexpr (MODE == 2) {
          outB[(long long)((m >> 11) * NH + (n >> 6)) * (S_LEN * 64) + (long long)(m & 2047) * 64 + (n & 63)] = f2b(v);
        } else if constexpr (MODE == 3) {
          outB[((long long)((m >> 11) * NH + (n >> 6)) * 64 + (n & 63)) * S_LEN + (m & 2047)] = f2b(v);
        }
      }
    }
}

// ---------------- Kernel A v3: one pass, pruned histogram + candidate spill ----------------
// grid (128, 16): 16 query rows per block. block = 256 (4 waves).
__global__ __launch_bounds__(256) void score_stats(
    const u16* __restrict__ Qb, const u16* __restrict__ Kb,
    float2* __restrict__ rowstats, unsigned* __restrict__ flagsG) {
  __shared__ u16 Qs[16 * 64];             // 2 KB swizzled
  __shared__ u16 Ks[128 * 64];            // 16 KB swizzled
  __shared__ unsigned hist[16][132];      // 8.25 KB, 128 linear bins (pad 132)
  __shared__ u16 cand[16][CAP];           // 24 KB candidate keys
  __shared__ unsigned cnt[16], curb[16], maxk[16], selB[16];
  int bh = blockIdx.y, m0 = blockIdx.x * 16, t = threadIdx.x;
  int lane = t & 63, wv = t >> 6, fr = lane & 15, fg = lane >> 4;
  const u16* Qg = Qb + ((long long)bh * S_LEN + m0) * 64;
  const u16* Kg = Kb + (long long)bh * S_LEN * 64;
  unsigned* hf = &hist[0][0];
  for (int i = t; i < 16 * 132; i += 256) hf[i] = 0u;
  unsigned* cf = (unsigned*)&cand[0][0];
  for (int i = t; i < 16 * CAP / 2; i += 256) cf[i] = 0u;
  if (t < 16) { cnt[t] = 0u; curb[t] = 0u; maxk[t] = 0u; }
  if (t < 128) {
    int row = t >> 3, cc = t & 7;
    *(u16x8*)&Qs[row * 64 + ((cc ^ (row & 7)) * 8)] = *(const u16x8*)&Qg[row * 64 + cc * 8];
  }
  __syncthreads();
  bf16x8 aq[2];
#pragma unroll
  for (int ks = 0; ks < 2; ks++)
    aq[ks] = *(const bf16x8*)&Qs[fr * 64 + (((fg + 4 * ks) ^ (fr & 7)) * 8)];

  float mx4[4] = {-3e38f, -3e38f, -3e38f, -3e38f};
  unsigned bcm[4] = {0u, 0u, 0u, 0u};
  bool ovf = false;

  // suffix-scan hist rows (wave wv owns rows wv*4..+3), update curb (and selB at end)
  auto scan_update = [&](bool storeSel) {
    __syncthreads();
    for (int rr = 0; rr < 4; rr++) {
      int row = wv * 4 + rr;
      unsigned h0 = hist[row][2 * lane], h1 = hist[row][2 * lane + 1];
      unsigned g2 = h0 + h1, suf = g2;
#pragma unroll
      for (int o = 1; o < 64; o <<= 1) {
        unsigned v = (unsigned)__shfl_down((int)suf, o);
        suf += (lane + o < 64) ? v : 0u;
      }
      unsigned above = suf - g2;           // count in bins > 2*lane+1
      unsigned c1 = above + h1;            // >= bin 2*lane+1
      unsigned c0 = c1 + h0;               // >= bin 2*lane
      if (c1 >= TOPK && above < TOPK) {
        curb[row] = (unsigned)(2 * lane + 1);
        if (storeSel) selB[row] = (unsigned)(2 * lane + 1);
      } else if (c0 >= TOPK && c1 < TOPK) {
        curb[row] = (unsigned)(2 * lane);
        if (storeSel) selB[row] = (unsigned)(2 * lane);
      }
    }
    __syncthreads();
  };
  auto refresh = [&] {
#pragma unroll
    for (int r = 0; r < 4; r++) {
      unsigned b = curb[fg * 4 + r];
      bcm[r] = b ? b - 1u : 0u;   // one-bin margin: superset of {key >= thr}
    }
  };

  auto do_tile = [&](int kt) {
    __syncthreads();
#pragma unroll
    for (int i = 0; i < 4; i++) {
      int c = t + 256 * i;
      int row = c >> 3, cc = c & 7;
      *(u16x8*)&Ks[row * 64 + ((cc ^ (row & 7)) * 8)] = *(const u16x8*)&Kg[(long long)(kt + row) * 64 + cc * 8];
    }
    __syncthreads();
#pragma unroll
    for (int g = 0; g < 2; g++) {
      int krow = g * 64 + wv * 16 + fr;
      f32x4 acc = {};
#pragma unroll
      for (int ks = 0; ks < 2; ks++) {
        bf16x8 bk = *(const bf16x8*)&Ks[krow * 64 + (((fg + 4 * ks) ^ (krow & 7)) * 8)];
        acc = __builtin_amdgcn_mfma_f32_16x16x32_bf16(aq[ks], bk, acc, 0, 0, 0);
      }
#pragma unroll
      for (int r = 0; r < 4; r++) {
        float s = acc[r] * 0.125f;
        mx4[r] = fmaxf(mx4[r], s);
        int bin = (int)floorf(s * 4.f) + 64;
        bin = bin < 0 ? 0 : (bin > 127 ? 127 : bin);
        if ((unsigned)bin >= bcm[r]) {
          int row = fg * 4 + r;
          atomicAdd(&hist[row][bin], 1u);
          unsigned slot = atomicAdd(&cnt[row], 1u);
          u16 b16 = f2b(s);
          u16 key = (u16)(b16 ^ ((b16 & 0x8000) ? 0xFFFFu : 0x8000u));
          if (slot < CAP) cand[row][slot] = key;
          else ovf = true;
        }
      }
    }
  };

  for (int tile = 0; tile < 16; ++tile) {
    do_tile(tile * 128);
    if (tile == 1 || tile == 4 || tile == 8) { scan_update(false); refresh(); }
  }
#pragma unroll
  for (int r = 0; r < 4; r++) atomicMax(&maxk[fg * 4 + r], kmap(mx4[r]));
  if (ovf) flagsG[bh * 128 + blockIdx.x] = 1u;
  scan_update(true);  // final, complete counts for bins >= b*

  // exact threshold: count-based binary search over candidates (wave per row)
  for (int rr = 0; rr < 4; rr++) {
    int row = wv * 4 + rr;
    const unsigned* cu = (const unsigned*)&cand[row][0];
    unsigned ck[6];
#pragma unroll
    for (int j = 0; j < 6; j++) ck[j] = cu[lane + 64 * j];
    int bstar = (int)selB[row];
    float bl = (bstar - 64) * 0.25f;
    unsigned mk = maxk[row];
    unsigned lo = (bstar == 0) ? 0u : (unsigned)max(0, (int)kmap(bl) - 2);
    unsigned hi = (bstar >= 127) ? 65535u : min(65535u, kmap(bl + 0.25f) + 2u);
    hi = min(hi, mk);
    if (hi < lo) { lo = 0u; hi = 65535u; }  // paranoia
    while (lo < hi) {
      unsigned mid = (lo + hi + 1) >> 1;
      int c = 0;
#pragma unroll
      for (int j = 0; j < 6; j++) {
        c += ((ck[j] & 0xFFFFu) >= mid) ? 1 : 0;
        c += ((ck[j] >> 16) >= mid) ? 1 : 0;
      }
#pragma unroll
      for (int o = 1; o < 64; o <<= 1) c += __shfl_xor(c, o);
      if (c >= (int)TOPK) lo = mid; else hi = mid - 1;
    }
    if (lane == 0)
      rowstats[(long long)bh * S_LEN + m0 + row] = make_float2(kunmap(lo), kunmap(mk));
  }
}

// ---------------- fallback: R3 2-pass radix select, only for flagged blocks ----------------
__global__ __launch_bounds__(256) void score_fallback(
    const u16* __restrict__ Qb, const u16* __restrict__ Kb, float2* __restrict__ rowstats,
    const unsigned* __restrict__ flagsG) {
  if (!flagsG[blockIdx.y * 128 + blockIdx.x]) return;
  __shared__ u16 Qs[16 * 64];
  __shared__ u16 Ks[128 * 64];
  __shared__ unsigned int hist[16][264];
  __shared__ unsigned int maxkS[16];
  __shared__ int selBS[16];
  __shared__ unsigned int selKS[16];
  int bh = blockIdx.y;
  int m0 = blockIdx.x * 16;
  int t = threadIdx.x;
  int lane = t & 63, wv = t >> 6;
  int fr = lane & 15, fg = lane >> 4;
  const u16* Qg = Qb + ((long long)bh * S_LEN + m0) * 64;
  const u16* Kg = Kb + (long long)bh * S_LEN * 64;
  unsigned int* hf = &hist[0][0];
  for (int i = t; i < 16 * 264; i += 256) hf[i] = 0u;
  if (t < 16) maxkS[t] = 0u;
  if (t < 128) {
    int row = t >> 3, cc = t & 7;
    *(u16x8*)&Qs[row * 64 + ((cc ^ (row & 7)) * 8)] = *(const u16x8*)&Qg[row * 64 + cc * 8];
  }
  __syncthreads();
  bf16x8 aq[2];
#pragma unroll
  for (int ks = 0; ks < 2; ks++)
    aq[ks] = *(const bf16x8*)&Qs[fr * 64 + (((fg + 4 * ks) ^ (fr & 7)) * 8)];

  auto scan_row = [&](const unsigned int* hr, unsigned int k, int& hitbin, unsigned int& krem) -> bool {
    uint4 hv = *(const uint4*)&hr[lane * 4];
    unsigned int g = hv.x + hv.y + hv.z + hv.w;
    unsigned int suf = g;
#pragma unroll
    for (int o = 1; o < 64; o <<= 1) {
      unsigned int v = (unsigned int)__shfl_down((int)suf, o);
      suf += (lane + o < 64) ? v : 0u;
    }
    unsigned int above = suf - g;
    unsigned int c3 = above + hv.w;
    unsigned int c2 = c3 + hv.z;
    unsigned int c1 = c2 + hv.y;
    unsigned int c0 = c1 + hv.x;
    if (c3 >= k && above < k) { hitbin = lane * 4 + 3; krem = k - above; return true; }
    if (c2 >= k && c3 < k)    { hitbin = lane * 4 + 2; krem = k - c3; return true; }
    if (c1 >= k && c2 < k)    { hitbin = lane * 4 + 1; krem = k - c2; return true; }
    if (c0 >= k && c1 < k)    { hitbin = lane * 4 + 0; krem = k - c1; return true; }
    return false;
  };

  unsigned int mx4[4] = {0u, 0u, 0u, 0u};
  for (int kt = 0; kt < S_LEN; kt += 128) {
    __syncthreads();
#pragma unroll
    for (int i = 0; i < 4; i++) {
      int c = t + 256 * i;
      int row = c >> 3, cc = c & 7;
      *(u16x8*)&Ks[row * 64 + ((cc ^ (row & 7)) * 8)] = *(const u16x8*)&Kg[(long long)(kt + row) * 64 + cc * 8];
    }
    __syncthreads();
#pragma unroll
    for (int g = 0; g < 2; g++) {
      int krow = g * 64 + wv * 16 + fr;
      f32x4 acc = {};
#pragma unroll
      for (int ks = 0; ks < 2; ks++) {
        bf16x8 bk = *(const bf16x8*)&Ks[krow * 64 + (((fg + 4 * ks) ^ (krow & 7)) * 8)];
        acc = __builtin_amdgcn_mfma_f32_16x16x32_bf16(aq[ks], bk, acc, 0, 0, 0);
      }
#pragma unroll
      for (int r = 0; r < 4; r++) {
        float s = acc[r] * 0.125f;
        u16 b = f2b(s);
        unsigned int key = (unsigned int)(u16)(b ^ ((b & 0x8000) ? 0xFFFFu : 0x8000u));
        mx4[r] = max(mx4[r], key);
        atomicAdd(&hist[fg * 4 + r][key >> 8], 1u);
      }
    }
  }
#pragma unroll
  for (int r = 0; r < 4; r++) atomicMax(&maxkS[fg * 4 + r], mx4[r]);
  __syncthreads();
  for (int rr = 0; rr < 4; rr++) {
    int row = wv * 4 + rr;
    int hb;
    unsigned int kr;
    if (scan_row(&hist[row][0], TOPK, hb, kr)) {
      selBS[row] = hb;
      selKS[row] = kr;
    }
  }
  __syncthreads();
  for (int i = t; i < 16 * 264; i += 256) hf[i] = 0u;
  int sb[4];
#pragma unroll
  for (int r = 0; r < 4; r++) sb[r] = selBS[fg * 4 + r];
  for (int kt = 0; kt < S_LEN; kt += 128) {
    __syncthreads();
#pragma unroll
    for (int i = 0; i < 4; i++) {
      int c = t + 256 * i;
      int row = c >> 3, cc = c & 7;
      *(u16x8*)&Ks[row * 64 + ((cc ^ (row & 7)) * 8)] = *(const u16x8*)&Kg[(long long)(kt + row) * 64 + cc * 8];
    }
    __syncthreads();
#pragma unroll
    for (int g = 0; g < 2; g++) {
      int krow = g * 64 + wv * 16 + fr;
      f32x4 acc = {};
#pragma unroll
      for (int ks = 0; ks < 2; ks++) {
        bf16x8 bk = *(const bf16x8*)&Ks[krow * 64 + (((fg + 4 * ks) ^ (krow & 7)) * 8)];
        acc = __builtin_amdgcn_mfma_f32_16x16x32_bf16(aq[ks], bk, acc, 0, 0, 0);
      }
#pragma unroll
      for (int r = 0; r < 4; r++) {
        float s = acc[r] * 0.125f;
        u16 b = f2b(s);
        unsigned int key = (unsigned int)(u16)(b ^ ((b & 0x8000) ? 0xFFFFu : 0x8000u));
        if ((int)(key >> 8) == sb[r]) atomicAdd(&hist[fg * 4 + r][key & 255u], 1u);
      }
    }
  }
  __syncthreads();
  for (int rr = 0; rr < 4; rr++) {
    int row = wv * 4 + rr;
    int hb;
    unsigned int kr;
    if (scan_row(&hist[row][0], selKS[row], hb, kr)) {
      unsigned int tk = ((unsigned int)selBS[row] << 8) | (unsigned int)hb;
      unsigned int mk = maxkS[row] & 0xFFFFu;
      rowstats[(long long)bh * S_LEN + m0 + row] = make_float2(kunmap(tk), kunmap(mk));
    }
  }
}

// ---------------- Kernel B: flash-style masked-softmax PV with recomputed scores ----------------
__global__ __launch_bounds__(512) void attn_pv(
    const u16* __restrict__ Qb, const u16* __restrict__ Kb, const u16* __restrict__ VTb,
    const float2* __restrict__ rowstats, u16* __restrict__ aoB) {
  __shared__ u16 Qs[128 * 64];
  __shared__ u16 Ks[32 * 64];
  __shared__ u16 Vs[64 * 32];
  __shared__ u16 Ps[128 * 32];
  __shared__ float2 st[128];
  int bh = blockIdx.y;
  int m0 = blockIdx.x * 128;
  int t = threadIdx.x;
  int lane = t & 63, wv = t >> 6;
  int fr = lane & 15, fg = lane >> 4;
  int mw = wv * 16;
  const u16* Qg = Qb + ((long long)bh * S_LEN + m0) * 64;
  const u16* Kg = Kb + (long long)bh * S_LEN * 64;
  const u16* Vg = VTb + (long long)bh * 64 * S_LEN;
#pragma unroll
  for (int i = 0; i < 2; i++) {
    int e = t * 2 + i;
    int row = e >> 3, cc = e & 7;
    *(u16x8*)&Qs[row * 64 + ((cc ^ (row & 7)) * 8)] = *(const u16x8*)&Qg[(long long)row * 64 + cc * 8];
  }
  if (t < 128) st[t] = rowstats[(long long)bh * S_LEN + m0 + t];
  __syncthreads();
  bf16x8 aq[2];
#pragma unroll
  for (int ks = 0; ks < 2; ks++) {
    int row = mw + fr;
    aq[ks] = *(const bf16x8*)&Qs[row * 64 + (((fg + 4 * ks) ^ (row & 7)) * 8)];
  }
  f32x4 acc_o[4] = {};
  float zk[4] = {};
  float2 stv[4];
#pragma unroll
  for (int r = 0; r < 4; r++) stv[r] = st[mw + fg * 4 + r];
  for (int kt = 0; kt < S_LEN; kt += 32) {
    if (t < 256) {
      int row = t >> 3, cc = t & 7;
      *(u16x8*)&Ks[row * 64 + ((cc ^ (row & 7)) * 8)] = *(const u16x8*)&Kg[(long long)(kt + row) * 64 + cc * 8];
    } else {
      int t2 = t - 256;
      int row = t2 >> 2, c = t2 & 3;
      *(u16x8*)&Vs[row * 32 + c * 8] = *(const u16x8*)&Vg[(long long)row * S_LEN + kt + c * 8];
    }
    __syncthreads();
    f32x4 acc_s[2] = {};
#pragma unroll
    for (int ks = 0; ks < 2; ks++)
#pragma unroll
      for (int j = 0; j < 2; j++) {
        int krow = j * 16 + fr;
        bf16x8 bk = *(const bf16x8*)&Ks[krow * 64 + (((fg + 4 * ks) ^ (krow & 7)) * 8)];
        acc_s[j] = __builtin_amdgcn_mfma_f32_16x16x32_bf16(aq[ks], bk, acc_s[j], 0, 0, 0);
      }
#pragma unroll
    for (int j = 0; j < 2; j++)
#pragma unroll
      for (int r = 0; r < 4; r++) {
        float s = acc_s[j][r] * 0.125f;
        float p = (s >= stv[r].x) ? __expf(s - stv[r].y) : 0.f;
        zk[r] += p;
        Ps[(mw + fg * 4 + r) * 32 + j * 16 + fr] = f2b(p);
      }
    bf16x8 pa = *(const bf16x8*)&Ps[(mw + fr) * 32 + fg * 8];
#pragma unroll
    for (int j = 0; j < 4; j++) {
      bf16x8 bv = *(const bf16x8*)&Vs[(j * 16 + fr) * 32 + fg * 8];
      acc_o[j] = __builtin_amdgcn_mfma_f32_16x16x32_bf16(pa, bv, acc_o[j], 0, 0, 0);
    }
    __syncthreads();
  }
#pragma unroll
  for (int r = 0; r < 4; r++) {
#pragma unroll
    for (int o = 1; o < 16; o <<= 1) zk[r] += __shfl_xor(zk[r], o);
    zk[r] = 1.f / zk[r];
  }
  int b = bh >> 3, h = bh & 7;
  long long ob = (long long)b * S_LEN * DMODEL + h * 64;
#pragma unroll
  for (int j = 0; j < 4; j++)
#pragma unroll
    for (int r = 0; r < 4; r++) {
      int row = m0 + mw + fg * 4 + r;
      int dk = j * 16 + fr;
      aoB[ob + (long long)row * DMODEL + dk] = f2b(acc_o[j][r] * zk[r]);
    }
}

// ---------------- residual + LayerNorm ----------------
__global__ __launch_bounds__(256) void resid_ln(const float* __restrict__ h, const float* __restrict__ fco,
                                                const float* __restrict__ g, const float* __restrict__ b,
                                                float* __restrict__ hout, u16* __restrict__ hbout) {
  __shared__ float red[4];
  int row = blockIdx.x;
  int t = threadIdx.x;
  long long base = (long long)row * 512;
  float v0 = h[base + t] + fco[base + t];
  float v1 = h[base + t + 256] + fco[base + t + 256];
  float s = v0 + v1;
#pragma unroll
  for (int o = 32; o > 0; o >>= 1) s += __shfl_down(s, o);
  if ((t & 63) == 0) red[t >> 6] = s;
  __syncthreads();
  float mu = (red[0] + red[1] + red[2] + red[3]) * (1.f / 512.f);
  float d0 = v0 - mu, d1 = v1 - mu;
  float q = d0 * d0 + d1 * d1;
#pragma unroll
  for (int o = 32; o > 0; o >>= 1) q += __shfl_down(q, o);
  __syncthreads();
  if ((t & 63) == 0) red[t >> 6] = q;
  __syncthreads();
  float var = (red[0] + red[1] + red[2] + red[3]) * (1.f / 512.f);
  float rs = rsqrtf(var + 1e-5f);
  float y0 = d0 * rs * g[t] + b[t];
  float y1 = d1 * rs * g[t + 256] + b[t + 256];
  hout[base + t] = y0;
  hout[base + t + 256] = y1;
  hbout[base + t] = f2b(y0);
  hbout[base + t + 256] = f2b(y1);
}

// ---------------- decoder ----------------
__global__ void decoder_k(const float* __restrict__ h, const float* __restrict__ W,
                          const float* __restrict__ bias, float* __restrict__ out) {
  int t = threadIdx.x;
  int b = t >> 6, j = t & 63;
  const float* hr = h + ((long long)b * S_LEN + (S_LEN - 1)) * DMODEL;
  float s = 0.f;
  for (int d = 0; d < DMODEL; d++) s += hr[d] * W[(long long)d * 64 + j];
  out[t] = s + bias[j];
}

extern "C" void kernel_launch(void* const* d_in, const int* in_sizes, int n_in,
                              void* d_out, int out_size, void* d_ws, size_t ws_size,
                              hipStream_t stream) {
  const float* x = (const float*)d_in[0];
  const float* enc_W = (const float*)d_in[1];
  const float* enc_b = (const float*)d_in[2];
  const float* Wq = (const float*)d_in[3];
  const float* bq = (const float*)d_in[4];
  const float* Wk = (const float*)d_in[5];
  const float* bk = (const float*)d_in[6];
  const float* Wv = (const float*)d_in[7];
  const float* bv = (const float*)d_in[8];
  const float* fcW = (const float*)d_in[9];
  const float* fcb = (const float*)d_in[10];
  const float* ln_g = (const float*)d_in[11];
  const float* ln_b = (const float*)d_in[12];
  const float* dec_W = (const float*)d_in[13];
  const float* dec_b = (const float*)d_in[14];

  char* p = (char*)d_ws;
  auto alloc = [&](size_t bytes) {
    char* r = p;
    p += (bytes + 255) & ~(size_t)255;
    return r;
  };
  const size_t BS = 2 * (size_t)S_LEN;
  u16* encWT = (u16*)alloc(512 * 64 * 2);
  u16* xbf = (u16*)alloc(BS * 64 * 2);
  float* hF = (float*)alloc(BS * 512 * 4);
  u16* hB = (u16*)alloc(BS * 512 * 2);
  u16* WqT = (u16*)alloc(512 * 512 * 2);
  u16* WkT = (u16*)alloc(512 * 512 * 2);
  u16* WvT = (u16*)alloc(512 * 512 * 2);
  u16* fcWT = (u16*)alloc(512 * 512 * 2);
  u16* Qb = (u16*)alloc((size_t)16 * 2048 * 64 * 2);
  u16* Kb = (u16*)alloc((size_t)16 * 2048 * 64 * 2);
  u16* VTb = (u16*)alloc((size_t)16 * 2048 * 64 * 2);
  float2* rstat = (float2*)alloc((size_t)16 * 2048 * 8);
  u16* aoB = (u16*)alloc(BS * 512 * 2);
  unsigned* flags = (unsigned*)alloc(2048 * 4);
  float* fcO = (float*)Qb;  // alias: Qb+Kb dead after attn_pv

  transpose_w<<<dim3(16, 2), 256, 0, stream>>>(enc_W, encWT, 64, 512);
  conv_b<<<(int)(BS * 64 / 256), 256, 0, stream>>>(x, xbf, (int)(BS * 64));
  gemm_bt<4><<<dim3(4, 32), 256, 0, stream>>>(xbf, encWT, enc_b, hF, hB, 4096, 512, 64, 1.f);

  for (int l = 0; l < 2; l++) {
    transpose_w4<<<dim3(16, 16, 4), 256, 0, stream>>>(
        Wq + (size_t)l * 512 * 512, Wk + (size_t)l * 512 * 512,
        Wv + (size_t)l * 512 * 512, fcW + (size_t)l * 512 * 512,
        WqT, WkT, WvT, fcWT);
    gemm_bt<2><<<dim3(4, 32), 256, 0, stream>>>(hB, WqT, bq + l * 512, nullptr, Qb, 4096, 512, 512, 1.f);
    gemm_bt<2><<<dim3(4, 32), 256, 0, stream>>>(hB, WkT, bk + l * 512, nullptr, Kb, 4096, 512, 512, 1.f);
    gemm_bt<3><<<dim3(4, 32), 256, 0, stream>>>(hB, WvT, bv + l * 512, nullptr, VTb, 4096, 512, 512, 1.f);
    hipMemsetAsync(flags, 0, 2048 * 4, stream);
    score_stats<<<dim3(128, 16), 256, 0, stream>>>(Qb, Kb, rstat, flags);
    score_fallback<<<dim3(128, 16), 256, 0, stream>>>(Qb, Kb, rstat, flags);
    attn_pv<<<dim3(16, 16), 512, 0, stream>>>(Qb, Kb, VTb, rstat, aoB);
    gemm_bt<0><<<dim3(4, 32), 256, 0, stream>>>(aoB, fcWT, fcb + l * 512, fcO, nullptr, 4096, 512, 512, 1.f);
    resid_ln<<<4096, 256, 0, stream>>>(hF, fcO, ln_g + l * 512, ln_b + l * 512, hF, hB);
  }
  decoder_k<<<1, 128, 0, stream>>>(hF, dec_W, dec_b, (float*)d_out);
}

// Round 5
// 510.476 us; speedup vs baseline: 1.7495x; 1.7495x over previous
//
#include <hip/hip_runtime.h>
#include <hip/hip_bf16.h>

typedef unsigned short u16;
typedef __bf16 bf16x8 __attribute__((ext_vector_type(8)));
typedef u16 u16x8 __attribute__((ext_vector_type(8)));
typedef float f32x4 __attribute__((ext_vector_type(4)));

#define S_LEN 2048
#define NH 8
#define DMODEL 512
#define TOPK 204

__device__ __forceinline__ u16 f2b(float f) {
  __hip_bfloat16 h = __float2bfloat16(f);
  return __builtin_bit_cast(u16, h);
}
__device__ __forceinline__ unsigned kmap16(u16 b) {
  return (unsigned)(u16)(b ^ ((b & 0x8000) ? 0xFFFFu : 0x8000u));
}
__device__ __forceinline__ float kunmap(unsigned k) {
  unsigned tb = (k & 0x8000u) ? (k ^ 0x8000u) : (~k & 0xFFFFu);
  return __uint_as_float(tb << 16);
}

// ---------------- transpose fp32 (R x C) -> bf16 (C x R) ----------------
__global__ void transpose_w(const float* __restrict__ in, u16* __restrict__ out, int R, int C) {
  __shared__ float tile[32][33];
  int c0 = blockIdx.x * 32, r0 = blockIdx.y * 32;
  int tx = threadIdx.x & 31, ty = threadIdx.x >> 5;
#pragma unroll
  for (int i = 0; i < 32; i += 8)
    tile[ty + i][tx] = in[(long long)(r0 + ty + i) * C + c0 + tx];
  __syncthreads();
#pragma unroll
  for (int i = 0; i < 32; i += 8)
    out[(long long)(c0 + ty + i) * R + r0 + tx] = f2b(tile[tx][ty + i]);
}

// 4 x (512x512) weight transposes in one launch
__global__ void transpose_w4(const float* __restrict__ W0, const float* __restrict__ W1,
                             const float* __restrict__ W2, const float* __restrict__ W3,
                             u16* __restrict__ O0, u16* __restrict__ O1,
                             u16* __restrict__ O2, u16* __restrict__ O3) {
  __shared__ float tile[32][33];
  const float* in;
  u16* out;
  switch (blockIdx.z) {
    case 0: in = W0; out = O0; break;
    case 1: in = W1; out = O1; break;
    case 2: in = W2; out = O2; break;
    default: in = W3; out = O3; break;
  }
  int c0 = blockIdx.x * 32, r0 = blockIdx.y * 32;
  int tx = threadIdx.x & 31, ty = threadIdx.x >> 5;
#pragma unroll
  for (int i = 0; i < 32; i += 8)
    tile[ty + i][tx] = in[(long long)(r0 + ty + i) * 512 + c0 + tx];
  __syncthreads();
#pragma unroll
  for (int i = 0; i < 32; i += 8)
    out[(long long)(c0 + ty + i) * 512 + r0 + tx] = f2b(tile[tx][ty + i]);
}

// ---------------- fp32 -> bf16 convert ----------------
__global__ void conv_b(const float* __restrict__ in, u16* __restrict__ out, int n) {
  int i = blockIdx.x * 256 + threadIdx.x;
  if (i < n) out[i] = f2b(in[i]);
}

// ---------------- generic bf16 GEMM: C = A(MxK) @ BT(NxK)^T * scale + bias ----------------
template <int MODE>
__global__ __launch_bounds__(256) void gemm_bt(
    const u16* __restrict__ A, const u16* __restrict__ BT, const float* __restrict__ bias,
    float* __restrict__ outF, u16* __restrict__ outB,
    int M, int N, int K, float scale) {
  __shared__ u16 As[128 * 32];
  __shared__ u16 Bs[128 * 32];
  int n0 = blockIdx.x * 128, m0 = blockIdx.y * 128;
  int t = threadIdx.x;
  int lane = t & 63, wv = t >> 6;
  int mw = (wv & 1) * 64, nw = (wv >> 1) * 64;
  int fr = lane & 15, fg = lane >> 4;
  f32x4 acc[4][4] = {};
  for (int kt = 0; kt < K; kt += 32) {
    int e0 = t * 8;
    int r0r = e0 >> 5, c0c = e0 & 31;
    int e1 = e0 + 2048;
    int r1r = e1 >> 5, c1c = e1 & 31;
    *(u16x8*)&As[e0] = *(const u16x8*)&A[(long long)(m0 + r0r) * K + kt + c0c];
    *(u16x8*)&As[e1] = *(const u16x8*)&A[(long long)(m0 + r1r) * K + kt + c1c];
    *(u16x8*)&Bs[e0] = *(const u16x8*)&BT[(long long)(n0 + r0r) * K + kt + c0c];
    *(u16x8*)&Bs[e1] = *(const u16x8*)&BT[(long long)(n0 + r1r) * K + kt + c1c];
    __syncthreads();
    bf16x8 af[4], bfv[4];
#pragma unroll
    for (int i = 0; i < 4; i++) af[i] = *(const bf16x8*)&As[(mw + i * 16 + fr) * 32 + fg * 8];
#pragma unroll
    for (int i = 0; i < 4; i++) bfv[i] = *(const bf16x8*)&Bs[(nw + i * 16 + fr) * 32 + fg * 8];
#pragma unroll
    for (int i = 0; i < 4; i++)
#pragma unroll
      for (int j = 0; j < 4; j++)
        acc[i][j] = __builtin_amdgcn_mfma_f32_16x16x32_bf16(af[i], bfv[j], acc[i][j], 0, 0, 0);
    __syncthreads();
  }
#pragma unroll
  for (int i = 0; i < 4; i++)
#pragma unroll
    for (int j = 0; j < 4; j++) {
      int mloc = mw + i * 16 + fg * 4;
      int n = n0 + nw + j * 16 + fr;
      float bvl = bias ? bias[n] : 0.f;
#pragma unroll
      for (int r = 0; r < 4; r++) {
        int m = m0 + mloc + r;
        float v = acc[i][j][r] * scale + bvl;
        if constexpr (MODE == 0) {
          outF[(long long)m * N + n] = v;
        } else if constexpr (MODE == 4) {
          outF[(long long)m * N + n] = v;
          outB[(long long)m * N + n] = f2b(v);
        } else if constexpr (MODE == 2) {
          outB[(long long)((m >> 11) * NH + (n >> 6)) * (S_LEN * 64) + (long long)(m & 2047) * 64 + (n & 63)] = f2b(v);
        } else if constexpr (MODE == 3) {
          outB[((long long)((m >> 11) * NH + (n >> 6)) * 64 + (n & 63)) * S_LEN + (m & 2047)] = f2b(v);
        }
      }
    }
}

// ---------------- Kernel A v5: one QK pass -> LDS keys -> register binary-search select ----------------
// grid (128, 16): 16 query rows per block. block = 512 (8 waves), each wave owns a
// 256-col strip in phase 1 and 2 rows in phase 2. No LDS atomics, no histograms.
__global__ __launch_bounds__(512) void score_stats(
    const u16* __restrict__ Qb, const u16* __restrict__ Kb, float2* __restrict__ rowstats) {
  __shared__ u16 Qs[16 * 64];    // 2 KB swizzled
  __shared__ u16 Ss[16 * 2048];  // 64 KB mapped keys, col-XOR swizzled per row
  int bh = blockIdx.y, m0 = blockIdx.x * 16, t = threadIdx.x;
  int lane = t & 63, wv = t >> 6, fr = lane & 15, fg = lane >> 4;
  const u16* Qg = Qb + ((long long)bh * S_LEN + m0) * 64;
  const u16* Kg = Kb + (long long)bh * S_LEN * 64;
  if (t < 128) {
    int row = t >> 3, cc = t & 7;
    *(u16x8*)&Qs[row * 64 + ((cc ^ (row & 7)) * 8)] = *(const u16x8*)&Qg[row * 64 + cc * 8];
  }
  __syncthreads();
  bf16x8 aq[2];
#pragma unroll
  for (int ks = 0; ks < 2; ks++)
    aq[ks] = *(const bf16x8*)&Qs[fr * 64 + (((fg + 4 * ks) ^ (fr & 7)) * 8)];

  // ---- phase 1: wave wv computes cols [wv*256, wv*256+255], B operand direct from global ----
#pragma unroll 4
  for (int tt = 0; tt < 16; tt++) {
    int col0 = wv * 256 + tt * 16;
    f32x4 acc = {};
#pragma unroll
    for (int ks = 0; ks < 2; ks++) {
      bf16x8 bk = *(const bf16x8*)&Kg[(long long)(col0 + fr) * 64 + ks * 32 + fg * 8];
      acc = __builtin_amdgcn_mfma_f32_16x16x32_bf16(aq[ks], bk, acc, 0, 0, 0);
    }
#pragma unroll
    for (int r = 0; r < 4; r++) {
      float s = acc[r] * 0.125f;
      u16 key = (u16)kmap16(f2b(s));
      int row = fg * 4 + r;
      Ss[row * 2048 + ((col0 + fr) ^ ((row & 15) << 3))] = key;
    }
  }
  __syncthreads();

  // ---- phase 2: wave wv selects threshold for rows wv*2, wv*2+1 ----
  for (int rr = wv * 2; rr < wv * 2 + 2; rr++) {
    const unsigned* cu = (const unsigned*)&Ss[rr * 2048];
    unsigned kp[16];
#pragma unroll
    for (int j = 0; j < 16; j++) kp[j] = cu[lane + 64 * j];
    unsigned mx = 0;
#pragma unroll
    for (int j = 0; j < 16; j++) {
      unsigned a = kp[j] & 0xFFFFu, b = kp[j] >> 16;
      mx = max(mx, max(a, b));
    }
#pragma unroll
    for (int o = 1; o < 64; o <<= 1) mx = max(mx, (unsigned)__shfl_xor((int)mx, o));
    // largest T with count(key >= T) >= TOPK  ==  TOPK-th largest key
    unsigned lo = 0, hi = mx;
    while (lo < hi) {
      unsigned mid = (lo + hi + 1) >> 1;
      int c = 0;
#pragma unroll
      for (int j = 0; j < 16; j++) {
        c += ((kp[j] & 0xFFFFu) >= mid) ? 1 : 0;
        c += ((kp[j] >> 16) >= mid) ? 1 : 0;
      }
#pragma unroll
      for (int o = 1; o < 64; o <<= 1) c += __shfl_xor(c, o);
      if (c >= TOPK) lo = mid; else hi = mid - 1;
    }
    if (lane == 0)
      rowstats[(long long)bh * S_LEN + m0 + rr] = make_float2(kunmap(lo), kunmap(mx));
  }
}

// ---------------- Kernel B: flash-style masked-softmax PV with recomputed scores ----------------
__global__ __launch_bounds__(512) void attn_pv(
    const u16* __restrict__ Qb, const u16* __restrict__ Kb, const u16* __restrict__ VTb,
    const float2* __restrict__ rowstats, u16* __restrict__ aoB) {
  __shared__ u16 Qs[128 * 64];
  __shared__ u16 Ks[32 * 64];
  __shared__ u16 Vs[64 * 32];
  __shared__ u16 Ps[128 * 32];
  __shared__ float2 st[128];
  int bh = blockIdx.y;
  int m0 = blockIdx.x * 128;
  int t = threadIdx.x;
  int lane = t & 63, wv = t >> 6;
  int fr = lane & 15, fg = lane >> 4;
  int mw = wv * 16;
  const u16* Qg = Qb + ((long long)bh * S_LEN + m0) * 64;
  const u16* Kg = Kb + (long long)bh * S_LEN * 64;
  const u16* Vg = VTb + (long long)bh * 64 * S_LEN;
#pragma unroll
  for (int i = 0; i < 2; i++) {
    int e = t * 2 + i;
    int row = e >> 3, cc = e & 7;
    *(u16x8*)&Qs[row * 64 + ((cc ^ (row & 7)) * 8)] = *(const u16x8*)&Qg[(long long)row * 64 + cc * 8];
  }
  if (t < 128) st[t] = rowstats[(long long)bh * S_LEN + m0 + t];
  __syncthreads();
  bf16x8 aq[2];
#pragma unroll
  for (int ks = 0; ks < 2; ks++) {
    int row = mw + fr;
    aq[ks] = *(const bf16x8*)&Qs[row * 64 + (((fg + 4 * ks) ^ (row & 7)) * 8)];
  }
  f32x4 acc_o[4] = {};
  float zk[4] = {};
  float2 stv[4];
#pragma unroll
  for (int r = 0; r < 4; r++) stv[r] = st[mw + fg * 4 + r];
  for (int kt = 0; kt < S_LEN; kt += 32) {
    if (t < 256) {
      int row = t >> 3, cc = t & 7;
      *(u16x8*)&Ks[row * 64 + ((cc ^ (row & 7)) * 8)] = *(const u16x8*)&Kg[(long long)(kt + row) * 64 + cc * 8];
    } else {
      int t2 = t - 256;
      int row = t2 >> 2, c = t2 & 3;
      *(u16x8*)&Vs[row * 32 + c * 8] = *(const u16x8*)&Vg[(long long)row * S_LEN + kt + c * 8];
    }
    __syncthreads();
    f32x4 acc_s[2] = {};
#pragma unroll
    for (int ks = 0; ks < 2; ks++)
#pragma unroll
      for (int j = 0; j < 2; j++) {
        int krow = j * 16 + fr;
        bf16x8 bk = *(const bf16x8*)&Ks[krow * 64 + (((fg + 4 * ks) ^ (krow & 7)) * 8)];
        acc_s[j] = __builtin_amdgcn_mfma_f32_16x16x32_bf16(aq[ks], bk, acc_s[j], 0, 0, 0);
      }
#pragma unroll
    for (int j = 0; j < 2; j++)
#pragma unroll
      for (int r = 0; r < 4; r++) {
        float s = acc_s[j][r] * 0.125f;
        float p = (s >= stv[r].x) ? __expf(s - stv[r].y) : 0.f;
        zk[r] += p;
        Ps[(mw + fg * 4 + r) * 32 + j * 16 + fr] = f2b(p);
      }
    bf16x8 pa = *(const bf16x8*)&Ps[(mw + fr) * 32 + fg * 8];
#pragma unroll
    for (int j = 0; j < 4; j++) {
      bf16x8 bv = *(const bf16x8*)&Vs[(j * 16 + fr) * 32 + fg * 8];
      acc_o[j] = __builtin_amdgcn_mfma_f32_16x16x32_bf16(pa, bv, acc_o[j], 0, 0, 0);
    }
    __syncthreads();
  }
#pragma unroll
  for (int r = 0; r < 4; r++) {
#pragma unroll
    for (int o = 1; o < 16; o <<= 1) zk[r] += __shfl_xor(zk[r], o);
    zk[r] = 1.f / zk[r];
  }
  int b = bh >> 3, h = bh & 7;
  long long ob = (long long)b * S_LEN * DMODEL + h * 64;
#pragma unroll
  for (int j = 0; j < 4; j++)
#pragma unroll
    for (int r = 0; r < 4; r++) {
      int row = m0 + mw + fg * 4 + r;
      int dk = j * 16 + fr;
      aoB[ob + (long long)row * DMODEL + dk] = f2b(acc_o[j][r] * zk[r]);
    }
}

// ---------------- residual + LayerNorm ----------------
__global__ __launch_bounds__(256) void resid_ln(const float* __restrict__ h, const float* __restrict__ fco,
                                                const float* __restrict__ g, const float* __restrict__ b,
                                                float* __restrict__ hout, u16* __restrict__ hbout) {
  __shared__ float red[4];
  int row = blockIdx.x;
  int t = threadIdx.x;
  long long base = (long long)row * 512;
  float v0 = h[base + t] + fco[base + t];
  float v1 = h[base + t + 256] + fco[base + t + 256];
  float s = v0 + v1;
#pragma unroll
  for (int o = 32; o > 0; o >>= 1) s += __shfl_down(s, o);
  if ((t & 63) == 0) red[t >> 6] = s;
  __syncthreads();
  float mu = (red[0] + red[1] + red[2] + red[3]) * (1.f / 512.f);
  float d0 = v0 - mu, d1 = v1 - mu;
  float q = d0 * d0 + d1 * d1;
#pragma unroll
  for (int o = 32; o > 0; o >>= 1) q += __shfl_down(q, o);
  __syncthreads();
  if ((t & 63) == 0) red[t >> 6] = q;
  __syncthreads();
  float var = (red[0] + red[1] + red[2] + red[3]) * (1.f / 512.f);
  float rs = rsqrtf(var + 1e-5f);
  float y0 = d0 * rs * g[t] + b[t];
  float y1 = d1 * rs * g[t + 256] + b[t + 256];
  hout[base + t] = y0;
  hout[base + t + 256] = y1;
  hbout[base + t] = f2b(y0);
  hbout[base + t + 256] = f2b(y1);
}

// ---------------- decoder ----------------
__global__ void decoder_k(const float* __restrict__ h, const float* __restrict__ W,
                          const float* __restrict__ bias, float* __restrict__ out) {
  int t = threadIdx.x;
  int b = t >> 6, j = t & 63;
  const float* hr = h + ((long long)b * S_LEN + (S_LEN - 1)) * DMODEL;
  float s = 0.f;
  for (int d = 0; d < DMODEL; d++) s += hr[d] * W[(long long)d * 64 + j];
  out[t] = s + bias[j];
}

extern "C" void kernel_launch(void* const* d_in, const int* in_sizes, int n_in,
                              void* d_out, int out_size, void* d_ws, size_t ws_size,
                              hipStream_t stream) {
  const float* x = (const float*)d_in[0];
  const float* enc_W = (const float*)d_in[1];
  const float* enc_b = (const float*)d_in[2];
  const float* Wq = (const float*)d_in[3];
  const float* bq = (const float*)d_in[4];
  const float* Wk = (const float*)d_in[5];
  const float* bk = (const float*)d_in[6];
  const float* Wv = (const float*)d_in[7];
  const float* bv = (const float*)d_in[8];
  const float* fcW = (const float*)d_in[9];
  const float* fcb = (const float*)d_in[10];
  const float* ln_g = (const float*)d_in[11];
  const float* ln_b = (const float*)d_in[12];
  const float* dec_W = (const float*)d_in[13];
  const float* dec_b = (const float*)d_in[14];

  char* p = (char*)d_ws;
  auto alloc = [&](size_t bytes) {
    char* r = p;
    p += (bytes + 255) & ~(size_t)255;
    return r;
  };
  const size_t BS = 2 * (size_t)S_LEN;
  u16* encWT = (u16*)alloc(512 * 64 * 2);
  u16* xbf = (u16*)alloc(BS * 64 * 2);
  float* hF = (float*)alloc(BS * 512 * 4);
  u16* hB = (u16*)alloc(BS * 512 * 2);
  u16* WqT = (u16*)alloc(512 * 512 * 2);
  u16* WkT = (u16*)alloc(512 * 512 * 2);
  u16* WvT = (u16*)alloc(512 * 512 * 2);
  u16* fcWT = (u16*)alloc(512 * 512 * 2);
  u16* Qb = (u16*)alloc((size_t)16 * 2048 * 64 * 2);
  u16* Kb = (u16*)alloc((size_t)16 * 2048 * 64 * 2);
  u16* VTb = (u16*)alloc((size_t)16 * 2048 * 64 * 2);
  float2* rstat = (float2*)alloc((size_t)16 * 2048 * 8);
  u16* aoB = (u16*)alloc(BS * 512 * 2);
  float* fcO = (float*)Qb;  // alias: Qb+Kb dead after attn_pv

  transpose_w<<<dim3(16, 2), 256, 0, stream>>>(enc_W, encWT, 64, 512);
  conv_b<<<(int)(BS * 64 / 256), 256, 0, stream>>>(x, xbf, (int)(BS * 64));
  gemm_bt<4><<<dim3(4, 32), 256, 0, stream>>>(xbf, encWT, enc_b, hF, hB, 4096, 512, 64, 1.f);

  for (int l = 0; l < 2; l++) {
    transpose_w4<<<dim3(16, 16, 4), 256, 0, stream>>>(
        Wq + (size_t)l * 512 * 512, Wk + (size_t)l * 512 * 512,
        Wv + (size_t)l * 512 * 512, fcW + (size_t)l * 512 * 512,
        WqT, WkT, WvT, fcWT);
    gemm_bt<2><<<dim3(4, 32), 256, 0, stream>>>(hB, WqT, bq + l * 512, nullptr, Qb, 4096, 512, 512, 1.f);
    gemm_bt<2><<<dim3(4, 32), 256, 0, stream>>>(hB, WkT, bk + l * 512, nullptr, Kb, 4096, 512, 512, 1.f);
    gemm_bt<3><<<dim3(4, 32), 256, 0, stream>>>(hB, WvT, bv + l * 512, nullptr, VTb, 4096, 512, 512, 1.f);
    score_stats<<<dim3(128, 16), 512, 0, stream>>>(Qb, Kb, rstat);
    attn_pv<<<dim3(16, 16), 512, 0, stream>>>(Qb, Kb, VTb, rstat, aoB);
    gemm_bt<0><<<dim3(4, 32), 256, 0, stream>>>(aoB, fcWT, fcb + l * 512, fcO, nullptr, 4096, 512, 512, 1.f);
    resid_ln<<<4096, 256, 0, stream>>>(hF, fcO, ln_g + l * 512, ln_b + l * 512, hF, hB);
  }
  decoder_k<<<1, 128, 0, stream>>>(hF, dec_W, dec_b, (float*)d_out);
}

// Round 6
// 508.026 us; speedup vs baseline: 1.7580x; 1.0048x over previous
//
#include <hip/hip_runtime.h>
#include <hip/hip_bf16.h>

typedef unsigned short u16;
typedef __bf16 bf16x8 __attribute__((ext_vector_type(8)));
typedef u16 u16x8 __attribute__((ext_vector_type(8)));
typedef float f32x4 __attribute__((ext_vector_type(4)));

#define S_LEN 2048
#define NH 8
#define DMODEL 512
#define TOPK 204

__device__ __forceinline__ u16 f2b(float f) {
  __hip_bfloat16 h = __float2bfloat16(f);
  return __builtin_bit_cast(u16, h);
}
__device__ __forceinline__ unsigned kmap16(u16 b) {
  return (unsigned)(u16)(b ^ ((b & 0x8000) ? 0xFFFFu : 0x8000u));
}
__device__ __forceinline__ float kunmap(unsigned k) {
  unsigned tb = (k & 0x8000u) ? (k ^ 0x8000u) : (~k & 0xFFFFu);
  return __uint_as_float(tb << 16);
}

// ---------------- transpose fp32 (R x C) -> bf16 (C x R) ----------------
__global__ void transpose_w(const float* __restrict__ in, u16* __restrict__ out, int R, int C) {
  __shared__ float tile[32][33];
  int c0 = blockIdx.x * 32, r0 = blockIdx.y * 32;
  int tx = threadIdx.x & 31, ty = threadIdx.x >> 5;
#pragma unroll
  for (int i = 0; i < 32; i += 8)
    tile[ty + i][tx] = in[(long long)(r0 + ty + i) * C + c0 + tx];
  __syncthreads();
#pragma unroll
  for (int i = 0; i < 32; i += 8)
    out[(long long)(c0 + ty + i) * R + r0 + tx] = f2b(tile[tx][ty + i]);
}

// 4 x (512x512) weight transposes in one launch
__global__ void transpose_w4(const float* __restrict__ W0, const float* __restrict__ W1,
                             const float* __restrict__ W2, const float* __restrict__ W3,
                             u16* __restrict__ O0, u16* __restrict__ O1,
                             u16* __restrict__ O2, u16* __restrict__ O3) {
  __shared__ float tile[32][33];
  const float* in;
  u16* out;
  switch (blockIdx.z) {
    case 0: in = W0; out = O0; break;
    case 1: in = W1; out = O1; break;
    case 2: in = W2; out = O2; break;
    default: in = W3; out = O3; break;
  }
  int c0 = blockIdx.x * 32, r0 = blockIdx.y * 32;
  int tx = threadIdx.x & 31, ty = threadIdx.x >> 5;
#pragma unroll
  for (int i = 0; i < 32; i += 8)
    tile[ty + i][tx] = in[(long long)(r0 + ty + i) * 512 + c0 + tx];
  __syncthreads();
#pragma unroll
  for (int i = 0; i < 32; i += 8)
    out[(long long)(c0 + ty + i) * 512 + r0 + tx] = f2b(tile[tx][ty + i]);
}

// ---------------- fp32 -> bf16 convert ----------------
__global__ void conv_b(const float* __restrict__ in, u16* __restrict__ out, int n) {
  int i = blockIdx.x * 256 + threadIdx.x;
  if (i < n) out[i] = f2b(in[i]);
}

// ---------------- generic bf16 GEMM: C = A(MxK) @ BT(NxK)^T * scale + bias ----------------
template <int MODE>
__global__ __launch_bounds__(256) void gemm_bt(
    const u16* __restrict__ A, const u16* __restrict__ BT, const float* __restrict__ bias,
    float* __restrict__ outF, u16* __restrict__ outB,
    int M, int N, int K, float scale) {
  __shared__ u16 As[128 * 32];
  __shared__ u16 Bs[128 * 32];
  int n0 = blockIdx.x * 128, m0 = blockIdx.y * 128;
  int t = threadIdx.x;
  int lane = t & 63, wv = t >> 6;
  int mw = (wv & 1) * 64, nw = (wv >> 1) * 64;
  int fr = lane & 15, fg = lane >> 4;
  f32x4 acc[4][4] = {};
  for (int kt = 0; kt < K; kt += 32) {
    int e0 = t * 8;
    int r0r = e0 >> 5, c0c = e0 & 31;
    int e1 = e0 + 2048;
    int r1r = e1 >> 5, c1c = e1 & 31;
    *(u16x8*)&As[e0] = *(const u16x8*)&A[(long long)(m0 + r0r) * K + kt + c0c];
    *(u16x8*)&As[e1] = *(const u16x8*)&A[(long long)(m0 + r1r) * K + kt + c1c];
    *(u16x8*)&Bs[e0] = *(const u16x8*)&BT[(long long)(n0 + r0r) * K + kt + c0c];
    *(u16x8*)&Bs[e1] = *(const u16x8*)&BT[(long long)(n0 + r1r) * K + kt + c1c];
    __syncthreads();
    bf16x8 af[4], bfv[4];
#pragma unroll
    for (int i = 0; i < 4; i++) af[i] = *(const bf16x8*)&As[(mw + i * 16 + fr) * 32 + fg * 8];
#pragma unroll
    for (int i = 0; i < 4; i++) bfv[i] = *(const bf16x8*)&Bs[(nw + i * 16 + fr) * 32 + fg * 8];
#pragma unroll
    for (int i = 0; i < 4; i++)
#pragma unroll
      for (int j = 0; j < 4; j++)
        acc[i][j] = __builtin_amdgcn_mfma_f32_16x16x32_bf16(af[i], bfv[j], acc[i][j], 0, 0, 0);
    __syncthreads();
  }
#pragma unroll
  for (int i = 0; i < 4; i++)
#pragma unroll
    for (int j = 0; j < 4; j++) {
      int mloc = mw + i * 16 + fg * 4;
      int n = n0 + nw + j * 16 + fr;
      float bvl = bias ? bias[n] : 0.f;
#pragma unroll
      for (int r = 0; r < 4; r++) {
        int m = m0 + mloc + r;
        float v = acc[i][j][r] * scale + bvl;
        if constexpr (MODE == 0) {
          outF[(long long)m * N + n] = v;
        } else if constexpr (MODE == 4) {
          outF[(long long)m * N + n] = v;
          outB[(long long)m * N + n] = f2b(v);
        } else if constexpr (MODE == 2) {
          outB[(long long)((m >> 11) * NH + (n >> 6)) * (S_LEN * 64) + (long long)(m & 2047) * 64 + (n & 63)] = f2b(v);
        } else if constexpr (MODE == 3) {
          outB[((long long)((m >> 11) * NH + (n >> 6)) * 64 + (n & 63)) * S_LEN + (m & 2047)] = f2b(v);
        }
      }
    }
}

// ---------------- Kernel A v6: one QK pass -> LDS keys -> ballot/popcount binary-search select ----------------
// grid (128, 16): 16 query rows per block. block = 512 (8 waves), each wave owns a
// 256-col strip in phase 1 and 2 rows in phase 2. No LDS atomics, no shuffle-reduce chains.
__global__ __launch_bounds__(512) void score_stats(
    const u16* __restrict__ Qb, const u16* __restrict__ Kb, float2* __restrict__ rowstats) {
  __shared__ u16 Qs[16 * 64];    // 2 KB swizzled
  __shared__ u16 Ss[16 * 2048];  // 64 KB mapped keys, col-XOR swizzled per row
  int bh = blockIdx.y, m0 = blockIdx.x * 16, t = threadIdx.x;
  int lane = t & 63, wv = t >> 6, fr = lane & 15, fg = lane >> 4;
  const u16* Qg = Qb + ((long long)bh * S_LEN + m0) * 64;
  const u16* Kg = Kb + (long long)bh * S_LEN * 64;
  if (t < 128) {
    int row = t >> 3, cc = t & 7;
    *(u16x8*)&Qs[row * 64 + ((cc ^ (row & 7)) * 8)] = *(const u16x8*)&Qg[row * 64 + cc * 8];
  }
  __syncthreads();
  bf16x8 aq[2];
#pragma unroll
  for (int ks = 0; ks < 2; ks++)
    aq[ks] = *(const bf16x8*)&Qs[fr * 64 + (((fg + 4 * ks) ^ (fr & 7)) * 8)];

  // ---- phase 1: wave wv computes cols [wv*256, wv*256+255], B operand direct from global ----
#pragma unroll 4
  for (int tt = 0; tt < 16; tt++) {
    int col0 = wv * 256 + tt * 16;
    f32x4 acc = {};
#pragma unroll
    for (int ks = 0; ks < 2; ks++) {
      bf16x8 bk = *(const bf16x8*)&Kg[(long long)(col0 + fr) * 64 + ks * 32 + fg * 8];
      acc = __builtin_amdgcn_mfma_f32_16x16x32_bf16(aq[ks], bk, acc, 0, 0, 0);
    }
#pragma unroll
    for (int r = 0; r < 4; r++) {
      float s = acc[r] * 0.125f;
      u16 key = (u16)kmap16(f2b(s));
      int row = fg * 4 + r;
      Ss[row * 2048 + ((col0 + fr) ^ ((row & 15) << 3))] = key;
    }
  }
  __syncthreads();

  // ---- phase 2: wave wv selects threshold for rows wv*2, wv*2+1 ----
  for (int rr = wv * 2; rr < wv * 2 + 2; rr++) {
    const unsigned* cu = (const unsigned*)&Ss[rr * 2048];
    unsigned k32[32];
#pragma unroll
    for (int j = 0; j < 16; j++) {
      unsigned w = cu[lane + 64 * j];
      k32[2 * j] = w & 0xFFFFu;
      k32[2 * j + 1] = w >> 16;
    }
    unsigned mx = 0;
#pragma unroll
    for (int j = 0; j < 32; j++) mx = max(mx, k32[j]);
#pragma unroll
    for (int o = 1; o < 64; o <<= 1) mx = max(mx, (unsigned)__shfl_xor((int)mx, o));
    // largest T with count(key >= T) >= TOPK == TOPK-th largest key.
    // count via ballot (v_cmp -> sgpr mask) + popcount (scalar pipe): no shuffle chains.
    unsigned lo = 0, hi = mx;
    while (lo < hi) {
      unsigned mid = (lo + hi + 1) >> 1;
      int c = 0;
#pragma unroll
      for (int j = 0; j < 32; j++)
        c += (int)__popcll(__ballot(k32[j] >= mid));
      if (c >= TOPK) lo = mid; else hi = mid - 1;
    }
    if (lane == 0)
      rowstats[(long long)bh * S_LEN + m0 + rr] = make_float2(kunmap(lo), kunmap(mx));
  }
}

// ---------------- Kernel B: flash-style masked-softmax PV with recomputed scores ----------------
__global__ __launch_bounds__(512) void attn_pv(
    const u16* __restrict__ Qb, const u16* __restrict__ Kb, const u16* __restrict__ VTb,
    const float2* __restrict__ rowstats, u16* __restrict__ aoB) {
  __shared__ u16 Qs[128 * 64];
  __shared__ u16 Ks[32 * 64];
  __shared__ u16 Vs[64 * 32];
  __shared__ u16 Ps[128 * 32];
  __shared__ float2 st[128];
  int bh = blockIdx.y;
  int m0 = blockIdx.x * 128;
  int t = threadIdx.x;
  int lane = t & 63, wv = t >> 6;
  int fr = lane & 15, fg = lane >> 4;
  int mw = wv * 16;
  const u16* Qg = Qb + ((long long)bh * S_LEN + m0) * 64;
  const u16* Kg = Kb + (long long)bh * S_LEN * 64;
  const u16* Vg = VTb + (long long)bh * 64 * S_LEN;
#pragma unroll
  for (int i = 0; i < 2; i++) {
    int e = t * 2 + i;
    int row = e >> 3, cc = e & 7;
    *(u16x8*)&Qs[row * 64 + ((cc ^ (row & 7)) * 8)] = *(const u16x8*)&Qg[(long long)row * 64 + cc * 8];
  }
  if (t < 128) st[t] = rowstats[(long long)bh * S_LEN + m0 + t];
  __syncthreads();
  bf16x8 aq[2];
#pragma unroll
  for (int ks = 0; ks < 2; ks++) {
    int row = mw + fr;
    aq[ks] = *(const bf16x8*)&Qs[row * 64 + (((fg + 4 * ks) ^ (row & 7)) * 8)];
  }
  f32x4 acc_o[4] = {};
  float zk[4] = {};
  float2 stv[4];
#pragma unroll
  for (int r = 0; r < 4; r++) stv[r] = st[mw + fg * 4 + r];
  for (int kt = 0; kt < S_LEN; kt += 32) {
    if (t < 256) {
      int row = t >> 3, cc = t & 7;
      *(u16x8*)&Ks[row * 64 + ((cc ^ (row & 7)) * 8)] = *(const u16x8*)&Kg[(long long)(kt + row) * 64 + cc * 8];
    } else {
      int t2 = t - 256;
      int row = t2 >> 2, c = t2 & 3;
      *(u16x8*)&Vs[row * 32 + c * 8] = *(const u16x8*)&Vg[(long long)row * S_LEN + kt + c * 8];
    }
    __syncthreads();
    f32x4 acc_s[2] = {};
#pragma unroll
    for (int ks = 0; ks < 2; ks++)
#pragma unroll
      for (int j = 0; j < 2; j++) {
        int krow = j * 16 + fr;
        bf16x8 bk = *(const bf16x8*)&Ks[krow * 64 + (((fg + 4 * ks) ^ (krow & 7)) * 8)];
        acc_s[j] = __builtin_amdgcn_mfma_f32_16x16x32_bf16(aq[ks], bk, acc_s[j], 0, 0, 0);
      }
#pragma unroll
    for (int j = 0; j < 2; j++)
#pragma unroll
      for (int r = 0; r < 4; r++) {
        float s = acc_s[j][r] * 0.125f;
        float p = (s >= stv[r].x) ? __expf(s - stv[r].y) : 0.f;
        zk[r] += p;
        Ps[(mw + fg * 4 + r) * 32 + j * 16 + fr] = f2b(p);
      }
    bf16x8 pa = *(const bf16x8*)&Ps[(mw + fr) * 32 + fg * 8];
#pragma unroll
    for (int j = 0; j < 4; j++) {
      bf16x8 bv = *(const bf16x8*)&Vs[(j * 16 + fr) * 32 + fg * 8];
      acc_o[j] = __builtin_amdgcn_mfma_f32_16x16x32_bf16(pa, bv, acc_o[j], 0, 0, 0);
    }
    __syncthreads();
  }
#pragma unroll
  for (int r = 0; r < 4; r++) {
#pragma unroll
    for (int o = 1; o < 16; o <<= 1) zk[r] += __shfl_xor(zk[r], o);
    zk[r] = 1.f / zk[r];
  }
  int b = bh >> 3, h = bh & 7;
  long long ob = (long long)b * S_LEN * DMODEL + h * 64;
#pragma unroll
  for (int j = 0; j < 4; j++)
#pragma unroll
    for (int r = 0; r < 4; r++) {
      int row = m0 + mw + fg * 4 + r;
      int dk = j * 16 + fr;
      aoB[ob + (long long)row * DMODEL + dk] = f2b(acc_o[j][r] * zk[r]);
    }
}

// ---------------- residual + LayerNorm ----------------
__global__ __launch_bounds__(256) void resid_ln(const float* __restrict__ h, const float* __restrict__ fco,
                                                const float* __restrict__ g, const float* __restrict__ b,
                                                float* __restrict__ hout, u16* __restrict__ hbout) {
  __shared__ float red[4];
  int row = blockIdx.x;
  int t = threadIdx.x;
  long long base = (long long)row * 512;
  float v0 = h[base + t] + fco[base + t];
  float v1 = h[base + t + 256] + fco[base + t + 256];
  float s = v0 + v1;
#pragma unroll
  for (int o = 32; o > 0; o >>= 1) s += __shfl_down(s, o);
  if ((t & 63) == 0) red[t >> 6] = s;
  __syncthreads();
  float mu = (red[0] + red[1] + red[2] + red[3]) * (1.f / 512.f);
  float d0 = v0 - mu, d1 = v1 - mu;
  float q = d0 * d0 + d1 * d1;
#pragma unroll
  for (int o = 32; o > 0; o >>= 1) q += __shfl_down(q, o);
  __syncthreads();
  if ((t & 63) == 0) red[t >> 6] = q;
  __syncthreads();
  float var = (red[0] + red[1] + red[2] + red[3]) * (1.f / 512.f);
  float rs = rsqrtf(var + 1e-5f);
  float y0 = d0 * rs * g[t] + b[t];
  float y1 = d1 * rs * g[t + 256] + b[t + 256];
  hout[base + t] = y0;
  hout[base + t + 256] = y1;
  hbout[base + t] = f2b(y0);
  hbout[base + t + 256] = f2b(y1);
}

// ---------------- decoder ----------------
__global__ void decoder_k(const float* __restrict__ h, const float* __restrict__ W,
                          const float* __restrict__ bias, float* __restrict__ out) {
  int t = threadIdx.x;
  int b = t >> 6, j = t & 63;
  const float* hr = h + ((long long)b * S_LEN + (S_LEN - 1)) * DMODEL;
  float s = 0.f;
  for (int d = 0; d < DMODEL; d++) s += hr[d] * W[(long long)d * 64 + j];
  out[t] = s + bias[j];
}

extern "C" void kernel_launch(void* const* d_in, const int* in_sizes, int n_in,
                              void* d_out, int out_size, void* d_ws, size_t ws_size,
                              hipStream_t stream) {
  const float* x = (const float*)d_in[0];
  const float* enc_W = (const float*)d_in[1];
  const float* enc_b = (const float*)d_in[2];
  const float* Wq = (const float*)d_in[3];
  const float* bq = (const float*)d_in[4];
  const float* Wk = (const float*)d_in[5];
  const float* bk = (const float*)d_in[6];
  const float* Wv = (const float*)d_in[7];
  const float* bv = (const float*)d_in[8];
  const float* fcW = (const float*)d_in[9];
  const float* fcb = (const float*)d_in[10];
  const float* ln_g = (const float*)d_in[11];
  const float* ln_b = (const float*)d_in[12];
  const float* dec_W = (const float*)d_in[13];
  const float* dec_b = (const float*)d_in[14];

  char* p = (char*)d_ws;
  auto alloc = [&](size_t bytes) {
    char* r = p;
    p += (bytes + 255) & ~(size_t)255;
    return r;
  };
  const size_t BS = 2 * (size_t)S_LEN;
  u16* encWT = (u16*)alloc(512 * 64 * 2);
  u16* xbf = (u16*)alloc(BS * 64 * 2);
  float* hF = (float*)alloc(BS * 512 * 4);
  u16* hB = (u16*)alloc(BS * 512 * 2);
  u16* WqT = (u16*)alloc(512 * 512 * 2);
  u16* WkT = (u16*)alloc(512 * 512 * 2);
  u16* WvT = (u16*)alloc(512 * 512 * 2);
  u16* fcWT = (u16*)alloc(512 * 512 * 2);
  u16* Qb = (u16*)alloc((size_t)16 * 2048 * 64 * 2);
  u16* Kb = (u16*)alloc((size_t)16 * 2048 * 64 * 2);
  u16* VTb = (u16*)alloc((size_t)16 * 2048 * 64 * 2);
  float2* rstat = (float2*)alloc((size_t)16 * 2048 * 8);
  u16* aoB = (u16*)alloc(BS * 512 * 2);
  float* fcO = (float*)Qb;  // alias: Qb+Kb dead after attn_pv

  transpose_w<<<dim3(16, 2), 256, 0, stream>>>(enc_W, encWT, 64, 512);
  conv_b<<<(int)(BS * 64 / 256), 256, 0, stream>>>(x, xbf, (int)(BS * 64));
  gemm_bt<4><<<dim3(4, 32), 256, 0, stream>>>(xbf, encWT, enc_b, hF, hB, 4096, 512, 64, 1.f);

  for (int l = 0; l < 2; l++) {
    transpose_w4<<<dim3(16, 16, 4), 256, 0, stream>>>(
        Wq + (size_t)l * 512 * 512, Wk + (size_t)l * 512 * 512,
        Wv + (size_t)l * 512 * 512, fcW + (size_t)l * 512 * 512,
        WqT, WkT, WvT, fcWT);
    gemm_bt<2><<<dim3(4, 32), 256, 0, stream>>>(hB, WqT, bq + l * 512, nullptr, Qb, 4096, 512, 512, 1.f);
    gemm_bt<2><<<dim3(4, 32), 256, 0, stream>>>(hB, WkT, bk + l * 512, nullptr, Kb, 4096, 512, 512, 1.f);
    gemm_bt<3><<<dim3(4, 32), 256, 0, stream>>>(hB, WvT, bv + l * 512, nullptr, VTb, 4096, 512, 512, 1.f);
    score_stats<<<dim3(128, 16), 512, 0, stream>>>(Qb, Kb, rstat);
    attn_pv<<<dim3(16, 16), 512, 0, stream>>>(Qb, Kb, VTb, rstat, aoB);
    gemm_bt<0><<<dim3(4, 32), 256, 0, stream>>>(aoB, fcWT, fcb + l * 512, fcO, nullptr, 4096, 512, 512, 1.f);
    resid_ln<<<4096, 256, 0, stream>>>(hF, fcO, ln_g + l * 512, ln_b + l * 512, hF, hB);
  }
  decoder_k<<<1, 128, 0, stream>>>(hF, dec_W, dec_b, (float*)d_out);
}

// Round 7
// 447.461 us; speedup vs baseline: 1.9959x; 1.1354x over previous
//
#include <hip/hip_runtime.h>
#include <hip/hip_bf16.h>

typedef unsigned short u16;
typedef __bf16 bf16x8 __attribute__((ext_vector_type(8)));
typedef u16 u16x8 __attribute__((ext_vector_type(8)));
typedef float f32x4 __attribute__((ext_vector_type(4)));

#define S_LEN 2048
#define NH 8
#define DMODEL 512
#define TOPK 204

__device__ __forceinline__ u16 f2b(float f) {
  __hip_bfloat16 h = __float2bfloat16(f);
  return __builtin_bit_cast(u16, h);
}
__device__ __forceinline__ unsigned kmap16(u16 b) {
  return (unsigned)(u16)(b ^ ((b & 0x8000) ? 0xFFFFu : 0x8000u));
}
__device__ __forceinline__ float kunmap(unsigned k) {
  unsigned tb = (k & 0x8000u) ? (k ^ 0x8000u) : (~k & 0xFFFFu);
  return __uint_as_float(tb << 16);
}

// ---------------- transpose fp32 (R x C) -> bf16 (C x R) ----------------
__global__ void transpose_w(const float* __restrict__ in, u16* __restrict__ out, int R, int C) {
  __shared__ float tile[32][33];
  int c0 = blockIdx.x * 32, r0 = blockIdx.y * 32;
  int tx = threadIdx.x & 31, ty = threadIdx.x >> 5;
#pragma unroll
  for (int i = 0; i < 32; i += 8)
    tile[ty + i][tx] = in[(long long)(r0 + ty + i) * C + c0 + tx];
  __syncthreads();
#pragma unroll
  for (int i = 0; i < 32; i += 8)
    out[(long long)(c0 + ty + i) * R + r0 + tx] = f2b(tile[tx][ty + i]);
}

// 4 x (512x512) weight transposes in one launch
__global__ void transpose_w4(const float* __restrict__ W0, const float* __restrict__ W1,
                             const float* __restrict__ W2, const float* __restrict__ W3,
                             u16* __restrict__ O0, u16* __restrict__ O1,
                             u16* __restrict__ O2, u16* __restrict__ O3) {
  __shared__ float tile[32][33];
  const float* in;
  u16* out;
  switch (blockIdx.z) {
    case 0: in = W0; out = O0; break;
    case 1: in = W1; out = O1; break;
    case 2: in = W2; out = O2; break;
    default: in = W3; out = O3; break;
  }
  int c0 = blockIdx.x * 32, r0 = blockIdx.y * 32;
  int tx = threadIdx.x & 31, ty = threadIdx.x >> 5;
#pragma unroll
  for (int i = 0; i < 32; i += 8)
    tile[ty + i][tx] = in[(long long)(r0 + ty + i) * 512 + c0 + tx];
  __syncthreads();
#pragma unroll
  for (int i = 0; i < 32; i += 8)
    out[(long long)(c0 + ty + i) * 512 + r0 + tx] = f2b(tile[tx][ty + i]);
}

// ---------------- fp32 -> bf16 convert ----------------
__global__ void conv_b(const float* __restrict__ in, u16* __restrict__ out, int n) {
  int i = blockIdx.x * 256 + threadIdx.x;
  if (i < n) out[i] = f2b(i < n ? in[i] : 0.f);
}

// ---------------- generic bf16 GEMM, BM=64 x BN=128 tiles (grid fills 256 CUs at M=4096,N=512) ----
// MODE 0: outF fp32 row-major
// MODE 2: outB bf16 at [b][h][s][dk] (Q/K layout), m=b*S+s, n=h*64+dk
// MODE 3: outB bf16 at [b*NH+h][dk][s] (V^T layout)
// MODE 4: outF fp32 + outB bf16 row-major
template <int MODE>
__global__ __launch_bounds__(256) void gemm_bt(
    const u16* __restrict__ A, const u16* __restrict__ BT, const float* __restrict__ bias,
    float* __restrict__ outF, u16* __restrict__ outB,
    int M, int N, int K, float scale) {
  __shared__ u16 As[64 * 32];
  __shared__ u16 Bs[128 * 32];
  int n0 = blockIdx.x * 128, m0 = blockIdx.y * 64;
  int t = threadIdx.x;
  int lane = t & 63, wv = t >> 6;
  int mw = (wv & 1) * 32, nw = (wv >> 1) * 64;
  int fr = lane & 15, fg = lane >> 4;
  f32x4 acc[2][4] = {};
  for (int kt = 0; kt < K; kt += 32) {
    int e0 = t * 8;
    int r0r = e0 >> 5, c0c = e0 & 31;
    int e1 = e0 + 2048;
    int r1r = e1 >> 5, c1c = e1 & 31;
    *(u16x8*)&As[e0] = *(const u16x8*)&A[(long long)(m0 + r0r) * K + kt + c0c];
    *(u16x8*)&Bs[e0] = *(const u16x8*)&BT[(long long)(n0 + r0r) * K + kt + c0c];
    *(u16x8*)&Bs[e1] = *(const u16x8*)&BT[(long long)(n0 + r1r) * K + kt + c1c];
    __syncthreads();
    bf16x8 af[2], bfv[4];
#pragma unroll
    for (int i = 0; i < 2; i++) af[i] = *(const bf16x8*)&As[(mw + i * 16 + fr) * 32 + fg * 8];
#pragma unroll
    for (int j = 0; j < 4; j++) bfv[j] = *(const bf16x8*)&Bs[(nw + j * 16 + fr) * 32 + fg * 8];
#pragma unroll
    for (int i = 0; i < 2; i++)
#pragma unroll
      for (int j = 0; j < 4; j++)
        acc[i][j] = __builtin_amdgcn_mfma_f32_16x16x32_bf16(af[i], bfv[j], acc[i][j], 0, 0, 0);
    __syncthreads();
  }
#pragma unroll
  for (int i = 0; i < 2; i++)
#pragma unroll
    for (int j = 0; j < 4; j++) {
      int mloc = mw + i * 16 + fg * 4;
      int n = n0 + nw + j * 16 + fr;
      float bvl = bias ? bias[n] : 0.f;
#pragma unroll
      for (int r = 0; r < 4; r++) {
        int m = m0 + mloc + r;
        float v = acc[i][j][r] * scale + bvl;
        if constexpr (MODE == 0) {
          outF[(long long)m * N + n] = v;
        } else if constexpr (MODE == 4) {
          outF[(long long)m * N + n] = v;
          outB[(long long)m * N + n] = f2b(v);
        } else if constexpr (MODE == 2) {
          outB[(long long)((m >> 11) * NH + (n >> 6)) * (S_LEN * 64) + (long long)(m & 2047) * 64 + (n & 63)] = f2b(v);
        } else if constexpr (MODE == 3) {
          outB[((long long)((m >> 11) * NH + (n >> 6)) * 64 + (n & 63)) * S_LEN + (m & 2047)] = f2b(v);
        }
      }
    }
}

// ---------------- merged kernel: QK scores -> exact top-k threshold -> masked softmax PV ----------------
// grid (128, 16): 16 query rows per block, one (b,h). block = 512 (8 waves).
// Phase 1: QK^T via MFMA, bf16 keys -> LDS (swizzled). Phase 2: ballot/popcount binary-search
// threshold per row. Phase 3: each wave PVs a 256-col K-slice reading P from the stored keys.
// Phase 4: cross-wave reduce of partial O and Z in the (dead) key region.
__global__ __launch_bounds__(512) void score_pv(
    const u16* __restrict__ Qb, const u16* __restrict__ Kb, const u16* __restrict__ VTb,
    u16* __restrict__ aoB) {
  __shared__ u16 Qs[16 * 64];    // 2 KB swizzled
  __shared__ u16 Ss[16 * 2048];  // 64 KB keys; reused as fp32 partial-O after phase 3
  __shared__ unsigned lokeyS[16];
  __shared__ float mS[16];
  __shared__ float zS[8 * 16];
  int bh = blockIdx.y, m0 = blockIdx.x * 16, t = threadIdx.x;
  int lane = t & 63, wv = t >> 6, fr = lane & 15, fg = lane >> 4;
  const u16* Qg = Qb + ((long long)bh * S_LEN + m0) * 64;
  const u16* Kg = Kb + (long long)bh * S_LEN * 64;
  const u16* Vg = VTb + (long long)bh * 64 * S_LEN;
  if (t < 128) {
    int row = t >> 3, cc = t & 7;
    *(u16x8*)&Qs[row * 64 + ((cc ^ (row & 7)) * 8)] = *(const u16x8*)&Qg[row * 64 + cc * 8];
  }
  __syncthreads();
  bf16x8 aq[2];
#pragma unroll
  for (int ks = 0; ks < 2; ks++)
    aq[ks] = *(const bf16x8*)&Qs[fr * 64 + (((fg + 4 * ks) ^ (fr & 7)) * 8)];

  // ---- phase 1: wave wv computes cols [wv*256, wv*256+255], keys to LDS ----
#pragma unroll 4
  for (int tt = 0; tt < 16; tt++) {
    int col0 = wv * 256 + tt * 16;
    f32x4 acc = {};
#pragma unroll
    for (int ks = 0; ks < 2; ks++) {
      bf16x8 bk = *(const bf16x8*)&Kg[(long long)(col0 + fr) * 64 + ks * 32 + fg * 8];
      acc = __builtin_amdgcn_mfma_f32_16x16x32_bf16(aq[ks], bk, acc, 0, 0, 0);
    }
#pragma unroll
    for (int r = 0; r < 4; r++) {
      float s = acc[r] * 0.125f;
      u16 key = (u16)kmap16(f2b(s));
      int row = fg * 4 + r;
      Ss[row * 2048 + ((col0 + fr) ^ ((row & 15) << 3))] = key;
    }
  }
  __syncthreads();

  // ---- phase 2: wave wv selects threshold for rows wv*2, wv*2+1 (ballot+popcount) ----
  for (int rr = wv * 2; rr < wv * 2 + 2; rr++) {
    const unsigned* cu = (const unsigned*)&Ss[rr * 2048];
    unsigned k32[32];
#pragma unroll
    for (int j = 0; j < 16; j++) {
      unsigned w = cu[lane + 64 * j];
      k32[2 * j] = w & 0xFFFFu;
      k32[2 * j + 1] = w >> 16;
    }
    unsigned mx = 0;
#pragma unroll
    for (int j = 0; j < 32; j++) mx = max(mx, k32[j]);
#pragma unroll
    for (int o = 1; o < 64; o <<= 1) mx = max(mx, (unsigned)__shfl_xor((int)mx, o));
    unsigned lo = 0, hi = mx;
    while (lo < hi) {
      unsigned mid = (lo + hi + 1) >> 1;
      int c = 0;
#pragma unroll
      for (int j = 0; j < 32; j++)
        c += (int)__popcll(__ballot(k32[j] >= mid));
      if (c >= TOPK) lo = mid; else hi = mid - 1;
    }
    if (lane == 0) {
      lokeyS[rr] = lo;
      mS[rr] = kunmap(mx);
    }
  }
  __syncthreads();

  // ---- phase 3: wave wv PVs its K-slice [wv*256, wv*256+255] from stored keys ----
  unsigned myLo = lokeyS[fr];
  float myM = mS[fr];
  float zpart = 0.f;
  f32x4 acc_o[4] = {};
#pragma unroll 2
  for (int step = 0; step < 8; step++) {
    int k0 = wv * 256 + step * 32;
    u16x8 kk = *(const u16x8*)&Ss[fr * 2048 + ((k0 + fg * 8) ^ ((fr & 15) << 3))];
    u16x8 wpa;
#pragma unroll
    for (int e = 0; e < 8; e++) {
      unsigned key = kk[e];
      float pv = 0.f;
      if (key >= myLo) pv = __expf(kunmap(key) - myM);
      zpart += pv;
      wpa[e] = f2b(pv);
    }
    bf16x8 pa = *(bf16x8*)&wpa;
#pragma unroll
    for (int j = 0; j < 4; j++) {
      bf16x8 bv = *(const bf16x8*)&Vg[(long long)(j * 16 + fr) * 2048 + k0 + fg * 8];
      acc_o[j] = __builtin_amdgcn_mfma_f32_16x16x32_bf16(pa, bv, acc_o[j], 0, 0, 0);
    }
  }
  // zpart holds row fr's partial over cols {k0+fg*8..+7} x 8 steps; sum over fg group
  zpart += __shfl_xor(zpart, 16);
  zpart += __shfl_xor(zpart, 32);
  __syncthreads();  // all waves done reading keys

  // ---- phase 4: write partials into dead key region, cross-wave reduce, output ----
  float* Of = (float*)Ss;  // 8 waves x [16][64] fp32 = 32 KB
#pragma unroll
  for (int j = 0; j < 4; j++)
#pragma unroll
    for (int r = 0; r < 4; r++)
      Of[wv * 1024 + (fg * 4 + r) * 64 + j * 16 + fr] = acc_o[j][r];
  if (fg == 0) zS[wv * 16 + fr] = zpart;
  __syncthreads();
  long long ob = (long long)(bh >> 3) * S_LEN * DMODEL + (bh & 7) * 64;
#pragma unroll
  for (int o = t; o < 1024; o += 512) {
    int row = o >> 6, dk = o & 63;
    float s = 0.f;
#pragma unroll
    for (int w = 0; w < 8; w++) s += Of[w * 1024 + o];
    float z = 0.f;
#pragma unroll
    for (int w = 0; w < 8; w++) z += zS[w * 16 + row];
    aoB[ob + (long long)(m0 + row) * DMODEL + dk] = f2b(s / z);
  }
}

// ---------------- residual + LayerNorm ----------------
__global__ __launch_bounds__(256) void resid_ln(const float* __restrict__ h, const float* __restrict__ fco,
                                                const float* __restrict__ g, const float* __restrict__ b,
                                                float* __restrict__ hout, u16* __restrict__ hbout) {
  __shared__ float red[4];
  int row = blockIdx.x;
  int t = threadIdx.x;
  long long base = (long long)row * 512;
  float v0 = h[base + t] + fco[base + t];
  float v1 = h[base + t + 256] + fco[base + t + 256];
  float s = v0 + v1;
#pragma unroll
  for (int o = 32; o > 0; o >>= 1) s += __shfl_down(s, o);
  if ((t & 63) == 0) red[t >> 6] = s;
  __syncthreads();
  float mu = (red[0] + red[1] + red[2] + red[3]) * (1.f / 512.f);
  float d0 = v0 - mu, d1 = v1 - mu;
  float q = d0 * d0 + d1 * d1;
#pragma unroll
  for (int o = 32; o > 0; o >>= 1) q += __shfl_down(q, o);
  __syncthreads();
  if ((t & 63) == 0) red[t >> 6] = q;
  __syncthreads();
  float var = (red[0] + red[1] + red[2] + red[3]) * (1.f / 512.f);
  float rs = rsqrtf(var + 1e-5f);
  float y0 = d0 * rs * g[t] + b[t];
  float y1 = d1 * rs * g[t + 256] + b[t + 256];
  hout[base + t] = y0;
  hout[base + t + 256] = y1;
  hbout[base + t] = f2b(y0);
  hbout[base + t + 256] = f2b(y1);
}

// ---------------- decoder ----------------
__global__ void decoder_k(const float* __restrict__ h, const float* __restrict__ W,
                          const float* __restrict__ bias, float* __restrict__ out) {
  int t = threadIdx.x;
  int b = t >> 6, j = t & 63;
  const float* hr = h + ((long long)b * S_LEN + (S_LEN - 1)) * DMODEL;
  float s = 0.f;
  for (int d = 0; d < DMODEL; d++) s += hr[d] * W[(long long)d * 64 + j];
  out[t] = s + bias[j];
}

extern "C" void kernel_launch(void* const* d_in, const int* in_sizes, int n_in,
                              void* d_out, int out_size, void* d_ws, size_t ws_size,
                              hipStream_t stream) {
  const float* x = (const float*)d_in[0];
  const float* enc_W = (const float*)d_in[1];
  const float* enc_b = (const float*)d_in[2];
  const float* Wq = (const float*)d_in[3];
  const float* bq = (const float*)d_in[4];
  const float* Wk = (const float*)d_in[5];
  const float* bk = (const float*)d_in[6];
  const float* Wv = (const float*)d_in[7];
  const float* bv = (const float*)d_in[8];
  const float* fcW = (const float*)d_in[9];
  const float* fcb = (const float*)d_in[10];
  const float* ln_g = (const float*)d_in[11];
  const float* ln_b = (const float*)d_in[12];
  const float* dec_W = (const float*)d_in[13];
  const float* dec_b = (const float*)d_in[14];

  char* p = (char*)d_ws;
  auto alloc = [&](size_t bytes) {
    char* r = p;
    p += (bytes + 255) & ~(size_t)255;
    return r;
  };
  const size_t BS = 2 * (size_t)S_LEN;
  u16* encWT = (u16*)alloc(512 * 64 * 2);
  u16* xbf = (u16*)alloc(BS * 64 * 2);
  float* hF = (float*)alloc(BS * 512 * 4);
  u16* hB = (u16*)alloc(BS * 512 * 2);
  u16* WqT = (u16*)alloc(512 * 512 * 2);
  u16* WkT = (u16*)alloc(512 * 512 * 2);
  u16* WvT = (u16*)alloc(512 * 512 * 2);
  u16* fcWT = (u16*)alloc(512 * 512 * 2);
  u16* Qb = (u16*)alloc((size_t)16 * 2048 * 64 * 2);
  u16* Kb = (u16*)alloc((size_t)16 * 2048 * 64 * 2);
  u16* VTb = (u16*)alloc((size_t)16 * 2048 * 64 * 2);
  u16* aoB = (u16*)alloc(BS * 512 * 2);
  float* fcO = (float*)Qb;  // alias: Qb+Kb (8 MB) dead after score_pv

  transpose_w<<<dim3(16, 2), 256, 0, stream>>>(enc_W, encWT, 64, 512);
  conv_b<<<(int)(BS * 64 / 256), 256, 0, stream>>>(x, xbf, (int)(BS * 64));
  gemm_bt<4><<<dim3(4, 64), 256, 0, stream>>>(xbf, encWT, enc_b, hF, hB, 4096, 512, 64, 1.f);

  for (int l = 0; l < 2; l++) {
    transpose_w4<<<dim3(16, 16, 4), 256, 0, stream>>>(
        Wq + (size_t)l * 512 * 512, Wk + (size_t)l * 512 * 512,
        Wv + (size_t)l * 512 * 512, fcW + (size_t)l * 512 * 512,
        WqT, WkT, WvT, fcWT);
    gemm_bt<2><<<dim3(4, 64), 256, 0, stream>>>(hB, WqT, bq + l * 512, nullptr, Qb, 4096, 512, 512, 1.f);
    gemm_bt<2><<<dim3(4, 64), 256, 0, stream>>>(hB, WkT, bk + l * 512, nullptr, Kb, 4096, 512, 512, 1.f);
    gemm_bt<3><<<dim3(4, 64), 256, 0, stream>>>(hB, WvT, bv + l * 512, nullptr, VTb, 4096, 512, 512, 1.f);
    score_pv<<<dim3(128, 16), 512, 0, stream>>>(Qb, Kb, VTb, aoB);
    gemm_bt<0><<<dim3(4, 64), 256, 0, stream>>>(aoB, fcWT, fcb + l * 512, fcO, nullptr, 4096, 512, 512, 1.f);
    resid_ln<<<4096, 256, 0, stream>>>(hF, fcO, ln_g + l * 512, ln_b + l * 512, hF, hB);
  }
  decoder_k<<<1, 128, 0, stream>>>(hF, dec_W, dec_b, (float*)d_out);
}

// Round 8
// 411.526 us; speedup vs baseline: 2.1702x; 1.0873x over previous
//
#include <hip/hip_runtime.h>
#include <hip/hip_bf16.h>

typedef unsigned short u16;
typedef __bf16 bf16x8 __attribute__((ext_vector_type(8)));
typedef u16 u16x8 __attribute__((ext_vector_type(8)));
typedef float f32x4 __attribute__((ext_vector_type(4)));

#define S_LEN 2048
#define NH 8
#define DMODEL 512
#define TOPK 204

__device__ __forceinline__ u16 f2b(float f) {
  __hip_bfloat16 h = __float2bfloat16(f);
  return __builtin_bit_cast(u16, h);
}
__device__ __forceinline__ unsigned kmap16(u16 b) {
  return (unsigned)(u16)(b ^ ((b & 0x8000) ? 0xFFFFu : 0x8000u));
}
__device__ __forceinline__ float kunmap(unsigned k) {
  unsigned tb = (k & 0x8000u) ? (k ^ 0x8000u) : (~k & 0xFFFFu);
  return __uint_as_float(tb << 16);
}

// ---------------- transpose fp32 (R x C) -> bf16 (C x R) ----------------
__global__ void transpose_w(const float* __restrict__ in, u16* __restrict__ out, int R, int C) {
  __shared__ float tile[32][33];
  int c0 = blockIdx.x * 32, r0 = blockIdx.y * 32;
  int tx = threadIdx.x & 31, ty = threadIdx.x >> 5;
#pragma unroll
  for (int i = 0; i < 32; i += 8)
    tile[ty + i][tx] = in[(long long)(r0 + ty + i) * C + c0 + tx];
  __syncthreads();
#pragma unroll
  for (int i = 0; i < 32; i += 8)
    out[(long long)(c0 + ty + i) * R + r0 + tx] = f2b(tile[tx][ty + i]);
}

// 4 x (512x512) weight transposes in one launch
__global__ void transpose_w4(const float* __restrict__ W0, const float* __restrict__ W1,
                             const float* __restrict__ W2, const float* __restrict__ W3,
                             u16* __restrict__ O0, u16* __restrict__ O1,
                             u16* __restrict__ O2, u16* __restrict__ O3) {
  __shared__ float tile[32][33];
  const float* in;
  u16* out;
  switch (blockIdx.z) {
    case 0: in = W0; out = O0; break;
    case 1: in = W1; out = O1; break;
    case 2: in = W2; out = O2; break;
    default: in = W3; out = O3; break;
  }
  int c0 = blockIdx.x * 32, r0 = blockIdx.y * 32;
  int tx = threadIdx.x & 31, ty = threadIdx.x >> 5;
#pragma unroll
  for (int i = 0; i < 32; i += 8)
    tile[ty + i][tx] = in[(long long)(r0 + ty + i) * 512 + c0 + tx];
  __syncthreads();
#pragma unroll
  for (int i = 0; i < 32; i += 8)
    out[(long long)(c0 + ty + i) * 512 + r0 + tx] = f2b(tile[tx][ty + i]);
}

// ---------------- fp32 -> bf16 convert ----------------
__global__ void conv_b(const float* __restrict__ in, u16* __restrict__ out, int n) {
  int i = blockIdx.x * 256 + threadIdx.x;
  if (i < n) out[i] = f2b(in[i]);
}

// ---------------- generic bf16 GEMM, BM=64 x BN=128 tiles ----------------
// MODE 0: outF fp32 row-major
// MODE 4: outF fp32 + outB bf16 row-major
// MODE 5: fused QKV (N=1536): seg=n>>9 -> Q(outB, QK layout) / K(outBK, QK layout) / V(outBV, V^T layout)
template <int MODE>
__global__ __launch_bounds__(256) void gemm_bt(
    const u16* __restrict__ A, const u16* __restrict__ BT,
    const float* __restrict__ bias, const float* __restrict__ biasK, const float* __restrict__ biasV,
    float* __restrict__ outF, u16* __restrict__ outB, u16* __restrict__ outBK, u16* __restrict__ outBV,
    int M, int N, int K, float scale) {
  __shared__ u16 As[64 * 32];
  __shared__ u16 Bs[128 * 32];
  int n0 = blockIdx.x * 128, m0 = blockIdx.y * 64;
  int t = threadIdx.x;
  int lane = t & 63, wv = t >> 6;
  int mw = (wv & 1) * 32, nw = (wv >> 1) * 64;
  int fr = lane & 15, fg = lane >> 4;
  f32x4 acc[2][4] = {};
  for (int kt = 0; kt < K; kt += 32) {
    int e0 = t * 8;
    int r0r = e0 >> 5, c0c = e0 & 31;
    int e1 = e0 + 2048;
    int r1r = e1 >> 5, c1c = e1 & 31;
    *(u16x8*)&As[e0] = *(const u16x8*)&A[(long long)(m0 + r0r) * K + kt + c0c];
    *(u16x8*)&Bs[e0] = *(const u16x8*)&BT[(long long)(n0 + r0r) * K + kt + c0c];
    *(u16x8*)&Bs[e1] = *(const u16x8*)&BT[(long long)(n0 + r1r) * K + kt + c1c];
    __syncthreads();
    bf16x8 af[2], bfv[4];
#pragma unroll
    for (int i = 0; i < 2; i++) af[i] = *(const bf16x8*)&As[(mw + i * 16 + fr) * 32 + fg * 8];
#pragma unroll
    for (int j = 0; j < 4; j++) bfv[j] = *(const bf16x8*)&Bs[(nw + j * 16 + fr) * 32 + fg * 8];
#pragma unroll
    for (int i = 0; i < 2; i++)
#pragma unroll
      for (int j = 0; j < 4; j++)
        acc[i][j] = __builtin_amdgcn_mfma_f32_16x16x32_bf16(af[i], bfv[j], acc[i][j], 0, 0, 0);
    __syncthreads();
  }
#pragma unroll
  for (int i = 0; i < 2; i++)
#pragma unroll
    for (int j = 0; j < 4; j++) {
      int mloc = mw + i * 16 + fg * 4;
      int n = n0 + nw + j * 16 + fr;
      float bvl;
      if constexpr (MODE == 5) {
        int seg = n >> 9, nn = n & 511;
        bvl = (seg == 0 ? bias : seg == 1 ? biasK : biasV)[nn];
      } else {
        bvl = bias ? bias[n] : 0.f;
      }
#pragma unroll
      for (int r = 0; r < 4; r++) {
        int m = m0 + mloc + r;
        float v = acc[i][j][r] * scale + bvl;
        if constexpr (MODE == 0) {
          outF[(long long)m * N + n] = v;
        } else if constexpr (MODE == 4) {
          outF[(long long)m * N + n] = v;
          outB[(long long)m * N + n] = f2b(v);
        } else if constexpr (MODE == 5) {
          int seg = n >> 9, nn = n & 511;
          u16 val = f2b(v);
          if (seg == 2) {
            outBV[((long long)((m >> 11) * NH + (nn >> 6)) * 64 + (nn & 63)) * S_LEN + (m & 2047)] = val;
          } else {
            long long qkidx = (long long)((m >> 11) * NH + (nn >> 6)) * (S_LEN * 64) +
                              (long long)(m & 2047) * 64 + (nn & 63);
            if (seg == 0) outB[qkidx] = val;
            else outBK[qkidx] = val;
          }
        }
      }
    }
}

// ---------------- merged kernel: QK scores -> exact top-k threshold -> masked softmax PV ----------------
// grid (128, 16): 16 query rows per block, one (b,h). block = 1024 (16 waves) for 32 waves/CU.
// Phase 1: QK^T via MFMA, bf16 keys -> LDS (swizzled); wave wv owns cols [wv*128, +127].
// Phase 2: wave wv selects threshold for row wv via ballot/popcount binary search.
// Phase 3: wave wv PVs its 128-col K-slice reading P from the stored keys.
// Phase 4: cross-wave reduce of partial O (in the dead key region, fg-swizzled) and Z.
__global__ __launch_bounds__(1024, 8) void score_pv(
    const u16* __restrict__ Qb, const u16* __restrict__ Kb, const u16* __restrict__ VTb,
    u16* __restrict__ aoB) {
  __shared__ u16 Qs[16 * 64];                       // 2 KB swizzled
  __shared__ __align__(16) u16 Ss[16 * 2048];       // 64 KB keys; reused as fp32 partial-O
  __shared__ unsigned lokeyS[16];
  __shared__ float mS[16];
  __shared__ float zS[16 * 16];
  int bh = blockIdx.y, m0 = blockIdx.x * 16, t = threadIdx.x;
  int lane = t & 63, wv = t >> 6, fr = lane & 15, fg = lane >> 4;
  const u16* Qg = Qb + ((long long)bh * S_LEN + m0) * 64;
  const u16* Kg = Kb + (long long)bh * S_LEN * 64;
  const u16* Vg = VTb + (long long)bh * 64 * S_LEN;
  if (t < 128) {
    int row = t >> 3, cc = t & 7;
    *(u16x8*)&Qs[row * 64 + ((cc ^ (row & 7)) * 8)] = *(const u16x8*)&Qg[row * 64 + cc * 8];
  }
  __syncthreads();
  bf16x8 aq[2];
#pragma unroll
  for (int ks = 0; ks < 2; ks++)
    aq[ks] = *(const bf16x8*)&Qs[fr * 64 + (((fg + 4 * ks) ^ (fr & 7)) * 8)];

  // ---- phase 1: wave wv computes cols [wv*128, wv*128+127], keys to LDS ----
#pragma unroll 4
  for (int tt = 0; tt < 8; tt++) {
    int col0 = wv * 128 + tt * 16;
    f32x4 acc = {};
#pragma unroll
    for (int ks = 0; ks < 2; ks++) {
      bf16x8 bk = *(const bf16x8*)&Kg[(long long)(col0 + fr) * 64 + ks * 32 + fg * 8];
      acc = __builtin_amdgcn_mfma_f32_16x16x32_bf16(aq[ks], bk, acc, 0, 0, 0);
    }
#pragma unroll
    for (int r = 0; r < 4; r++) {
      float s = acc[r] * 0.125f;
      u16 key = (u16)kmap16(f2b(s));
      int row = fg * 4 + r;
      Ss[row * 2048 + ((col0 + fr) ^ ((row & 15) << 3))] = key;
    }
  }
  __syncthreads();

  // ---- phase 2: wave wv selects threshold for row wv (ballot+popcount binary search) ----
  {
    int rr = wv;
    const unsigned* cu = (const unsigned*)&Ss[rr * 2048];
    unsigned k32[32];
#pragma unroll
    for (int j = 0; j < 16; j++) {
      unsigned w = cu[lane + 64 * j];
      k32[2 * j] = w & 0xFFFFu;
      k32[2 * j + 1] = w >> 16;
    }
    unsigned mx = 0;
#pragma unroll
    for (int j = 0; j < 32; j++) mx = max(mx, k32[j]);
#pragma unroll
    for (int o = 1; o < 64; o <<= 1) mx = max(mx, (unsigned)__shfl_xor((int)mx, o));
    unsigned lo = 0, hi = mx;
    while (lo < hi) {
      unsigned mid = (lo + hi + 1) >> 1;
      int c = 0;
#pragma unroll
      for (int j = 0; j < 32; j++)
        c += (int)__popcll(__ballot(k32[j] >= mid));
      if (c >= TOPK) lo = mid; else hi = mid - 1;
    }
    if (lane == 0) {
      lokeyS[rr] = lo;
      mS[rr] = kunmap(mx);
    }
  }
  __syncthreads();

  // ---- phase 3: wave wv PVs its K-slice [wv*128, wv*128+127] from stored keys ----
  unsigned myLo = lokeyS[fr];
  float myM = mS[fr];
  float zpart = 0.f;
  f32x4 acc_o[4] = {};
#pragma unroll 2
  for (int step = 0; step < 4; step++) {
    int k0 = wv * 128 + step * 32;
    u16x8 kk = *(const u16x8*)&Ss[fr * 2048 + ((k0 + fg * 8) ^ ((fr & 15) << 3))];
    u16x8 wpa;
#pragma unroll
    for (int e = 0; e < 8; e++) {
      unsigned key = kk[e];
      float pv = 0.f;
      if (key >= myLo) pv = __expf(kunmap(key) - myM);
      zpart += pv;
      wpa[e] = f2b(pv);
    }
    bf16x8 pa = *(bf16x8*)&wpa;
#pragma unroll
    for (int j = 0; j < 4; j++) {
      bf16x8 bv = *(const bf16x8*)&Vg[(long long)(j * 16 + fr) * 2048 + k0 + fg * 8];
      acc_o[j] = __builtin_amdgcn_mfma_f32_16x16x32_bf16(pa, bv, acc_o[j], 0, 0, 0);
    }
  }
  // zpart holds row fr's partial over this wave's cols; sum over the fg group
  zpart += __shfl_xor(zpart, 16);
  zpart += __shfl_xor(zpart, 32);
  __syncthreads();  // all waves done reading keys

  // ---- phase 4: partials into dead key region (fg-swizzled), cross-wave reduce, output ----
  float* Of = (float*)Ss;  // 16 waves x [16][64] fp32 = 64 KB
#pragma unroll
  for (int j = 0; j < 4; j++)
#pragma unroll
    for (int r = 0; r < 4; r++) {
      int row = fg * 4 + r, col = j * 16 + fr;
      Of[wv * 1024 + row * 64 + (col ^ ((row >> 2) << 3))] = acc_o[j][r];
    }
  if (fg == 0) zS[wv * 16 + fr] = zpart;
  __syncthreads();
  long long ob = (long long)(bh >> 3) * S_LEN * DMODEL + (bh & 7) * 64;
  {
    int row = t >> 6, dk = t & 63;
    int sw = dk ^ ((row >> 2) << 3);
    float s = 0.f;
#pragma unroll
    for (int w = 0; w < 16; w++) s += Of[w * 1024 + row * 64 + sw];
    float z = 0.f;
#pragma unroll
    for (int w = 0; w < 16; w++) z += zS[w * 16 + row];
    aoB[ob + (long long)(m0 + row) * DMODEL + dk] = f2b(s / z);
  }
}

// ---------------- residual + LayerNorm ----------------
__global__ __launch_bounds__(256) void resid_ln(const float* __restrict__ h, const float* __restrict__ fco,
                                                const float* __restrict__ g, const float* __restrict__ b,
                                                float* __restrict__ hout, u16* __restrict__ hbout) {
  __shared__ float red[4];
  int row = blockIdx.x;
  int t = threadIdx.x;
  long long base = (long long)row * 512;
  float v0 = h[base + t] + fco[base + t];
  float v1 = h[base + t + 256] + fco[base + t + 256];
  float s = v0 + v1;
#pragma unroll
  for (int o = 32; o > 0; o >>= 1) s += __shfl_down(s, o);
  if ((t & 63) == 0) red[t >> 6] = s;
  __syncthreads();
  float mu = (red[0] + red[1] + red[2] + red[3]) * (1.f / 512.f);
  float d0 = v0 - mu, d1 = v1 - mu;
  float q = d0 * d0 + d1 * d1;
#pragma unroll
  for (int o = 32; o > 0; o >>= 1) q += __shfl_down(q, o);
  __syncthreads();
  if ((t & 63) == 0) red[t >> 6] = q;
  __syncthreads();
  float var = (red[0] + red[1] + red[2] + red[3]) * (1.f / 512.f);
  float rs = rsqrtf(var + 1e-5f);
  float y0 = d0 * rs * g[t] + b[t];
  float y1 = d1 * rs * g[t + 256] + b[t + 256];
  hout[base + t] = y0;
  hout[base + t + 256] = y1;
  hbout[base + t] = f2b(y0);
  hbout[base + t + 256] = f2b(y1);
}

// ---------------- decoder ----------------
__global__ void decoder_k(const float* __restrict__ h, const float* __restrict__ W,
                          const float* __restrict__ bias, float* __restrict__ out) {
  int t = threadIdx.x;
  int b = t >> 6, j = t & 63;
  const float* hr = h + ((long long)b * S_LEN + (S_LEN - 1)) * DMODEL;
  float s = 0.f;
  for (int d = 0; d < DMODEL; d++) s += hr[d] * W[(long long)d * 64 + j];
  out[t] = s + bias[j];
}

extern "C" void kernel_launch(void* const* d_in, const int* in_sizes, int n_in,
                              void* d_out, int out_size, void* d_ws, size_t ws_size,
                              hipStream_t stream) {
  const float* x = (const float*)d_in[0];
  const float* enc_W = (const float*)d_in[1];
  const float* enc_b = (const float*)d_in[2];
  const float* Wq = (const float*)d_in[3];
  const float* bq = (const float*)d_in[4];
  const float* Wk = (const float*)d_in[5];
  const float* bk = (const float*)d_in[6];
  const float* Wv = (const float*)d_in[7];
  const float* bv = (const float*)d_in[8];
  const float* fcW = (const float*)d_in[9];
  const float* fcb = (const float*)d_in[10];
  const float* ln_g = (const float*)d_in[11];
  const float* ln_b = (const float*)d_in[12];
  const float* dec_W = (const float*)d_in[13];
  const float* dec_b = (const float*)d_in[14];

  char* p = (char*)d_ws;
  auto alloc = [&](size_t bytes) {
    char* r = p;
    p += (bytes + 255) & ~(size_t)255;
    return r;
  };
  const size_t BS = 2 * (size_t)S_LEN;
  u16* encWT = (u16*)alloc(512 * 64 * 2);
  u16* xbf = (u16*)alloc(BS * 64 * 2);
  float* hF = (float*)alloc(BS * 512 * 4);
  u16* hB = (u16*)alloc(BS * 512 * 2);
  u16* WqT = (u16*)alloc(512 * 512 * 2);   // WqT/WkT/WvT contiguous => one [1536][512] B matrix
  u16* WkT = (u16*)alloc(512 * 512 * 2);
  u16* WvT = (u16*)alloc(512 * 512 * 2);
  u16* fcWT = (u16*)alloc(512 * 512 * 2);
  u16* Qb = (u16*)alloc((size_t)16 * 2048 * 64 * 2);
  u16* Kb = (u16*)alloc((size_t)16 * 2048 * 64 * 2);
  u16* VTb = (u16*)alloc((size_t)16 * 2048 * 64 * 2);
  u16* aoB = (u16*)alloc(BS * 512 * 2);
  float* fcO = (float*)Qb;  // alias: Qb+Kb (8 MB) dead after score_pv

  transpose_w<<<dim3(16, 2), 256, 0, stream>>>(enc_W, encWT, 64, 512);
  conv_b<<<(int)(BS * 64 / 256), 256, 0, stream>>>(x, xbf, (int)(BS * 64));
  gemm_bt<4><<<dim3(4, 64), 256, 0, stream>>>(xbf, encWT, enc_b, nullptr, nullptr,
                                              hF, hB, nullptr, nullptr, 4096, 512, 64, 1.f);

  for (int l = 0; l < 2; l++) {
    transpose_w4<<<dim3(16, 16, 4), 256, 0, stream>>>(
        Wq + (size_t)l * 512 * 512, Wk + (size_t)l * 512 * 512,
        Wv + (size_t)l * 512 * 512, fcW + (size_t)l * 512 * 512,
        WqT, WkT, WvT, fcWT);
    gemm_bt<5><<<dim3(12, 64), 256, 0, stream>>>(hB, WqT, bq + l * 512, bk + l * 512, bv + l * 512,
                                                 nullptr, Qb, Kb, VTb, 4096, 1536, 512, 1.f);
    score_pv<<<dim3(128, 16), 1024, 0, stream>>>(Qb, Kb, VTb, aoB);
    gemm_bt<0><<<dim3(4, 64), 256, 0, stream>>>(aoB, fcWT, fcb + l * 512, nullptr, nullptr,
                                                fcO, nullptr, nullptr, nullptr, 4096, 512, 512, 1.f);
    resid_ln<<<4096, 256, 0, stream>>>(hF, fcO, ln_g + l * 512, ln_b + l * 512, hF, hB);
  }
  decoder_k<<<1, 128, 0, stream>>>(hF, dec_W, dec_b, (float*)d_out);
}

// Round 9
// 387.159 us; speedup vs baseline: 2.3068x; 1.0629x over previous
//
#include <hip/hip_runtime.h>
#include <hip/hip_bf16.h>

typedef unsigned short u16;
typedef __bf16 bf16x8 __attribute__((ext_vector_type(8)));
typedef u16 u16x8 __attribute__((ext_vector_type(8)));
typedef float f32x4 __attribute__((ext_vector_type(4)));

#define S_LEN 2048
#define NH 8
#define DMODEL 512
#define TOPK 204

__device__ __forceinline__ u16 f2b(float f) {
  __hip_bfloat16 h = __float2bfloat16(f);
  return __builtin_bit_cast(u16, h);
}
// fast RNE float->bf16 for finite values (bit-identical to __float2bfloat16 on non-NaN)
__device__ __forceinline__ unsigned f2b_fast(float f) {
  unsigned u = __float_as_uint(f);
  return (u + 0x7FFFu + ((u >> 16) & 1u)) >> 16;
}
__device__ __forceinline__ float kunmap(unsigned k) {
  unsigned tb = (k & 0x8000u) ? (k ^ 0x8000u) : (~k & 0xFFFFu);
  return __uint_as_float(tb << 16);
}
// float (bf16-valued) -> 16-bit monotone code
__device__ __forceinline__ unsigned fkmap(float f) {
  unsigned b = __float_as_uint(f) >> 16;
  return b ^ ((b & 0x8000u) ? 0xFFFFu : 0x8000u);
}

// ---------------- transpose fp32 (R x C) -> bf16 (C x R) ----------------
__global__ void transpose_w(const float* __restrict__ in, u16* __restrict__ out, int R, int C) {
  __shared__ float tile[32][33];
  int c0 = blockIdx.x * 32, r0 = blockIdx.y * 32;
  int tx = threadIdx.x & 31, ty = threadIdx.x >> 5;
#pragma unroll
  for (int i = 0; i < 32; i += 8)
    tile[ty + i][tx] = in[(long long)(r0 + ty + i) * C + c0 + tx];
  __syncthreads();
#pragma unroll
  for (int i = 0; i < 32; i += 8)
    out[(long long)(c0 + ty + i) * R + r0 + tx] = f2b(tile[tx][ty + i]);
}

// 4 x (512x512) weight transposes in one launch
__global__ void transpose_w4(const float* __restrict__ W0, const float* __restrict__ W1,
                             const float* __restrict__ W2, const float* __restrict__ W3,
                             u16* __restrict__ O0, u16* __restrict__ O1,
                             u16* __restrict__ O2, u16* __restrict__ O3) {
  __shared__ float tile[32][33];
  const float* in;
  u16* out;
  switch (blockIdx.z) {
    case 0: in = W0; out = O0; break;
    case 1: in = W1; out = O1; break;
    case 2: in = W2; out = O2; break;
    default: in = W3; out = O3; break;
  }
  int c0 = blockIdx.x * 32, r0 = blockIdx.y * 32;
  int tx = threadIdx.x & 31, ty = threadIdx.x >> 5;
#pragma unroll
  for (int i = 0; i < 32; i += 8)
    tile[ty + i][tx] = in[(long long)(r0 + ty + i) * 512 + c0 + tx];
  __syncthreads();
#pragma unroll
  for (int i = 0; i < 32; i += 8)
    out[(long long)(c0 + ty + i) * 512 + r0 + tx] = f2b(tile[tx][ty + i]);
}

// ---------------- fp32 -> bf16 convert ----------------
__global__ void conv_b(const float* __restrict__ in, u16* __restrict__ out, int n) {
  int i = blockIdx.x * 256 + threadIdx.x;
  if (i < n) out[i] = f2b(in[i]);
}

// ---------------- generic bf16 GEMM, BM=64 x BN=128 tiles ----------------
// MODE 0: outF fp32 row-major
// MODE 4: outF fp32 + outB bf16 row-major
// MODE 5: fused QKV (N=1536): seg=n>>9 -> Q(outB, QK layout, PRESCALED by 1/8) /
//         K(outBK, QK layout) / V(outBV, V^T layout)
template <int MODE>
__global__ __launch_bounds__(256) void gemm_bt(
    const u16* __restrict__ A, const u16* __restrict__ BT,
    const float* __restrict__ bias, const float* __restrict__ biasK, const float* __restrict__ biasV,
    float* __restrict__ outF, u16* __restrict__ outB, u16* __restrict__ outBK, u16* __restrict__ outBV,
    int M, int N, int K, float scale) {
  __shared__ u16 As[64 * 32];
  __shared__ u16 Bs[128 * 32];
  int n0 = blockIdx.x * 128, m0 = blockIdx.y * 64;
  int t = threadIdx.x;
  int lane = t & 63, wv = t >> 6;
  int mw = (wv & 1) * 32, nw = (wv >> 1) * 64;
  int fr = lane & 15, fg = lane >> 4;
  f32x4 acc[2][4] = {};
  for (int kt = 0; kt < K; kt += 32) {
    int e0 = t * 8;
    int r0r = e0 >> 5, c0c = e0 & 31;
    int e1 = e0 + 2048;
    int r1r = e1 >> 5, c1c = e1 & 31;
    *(u16x8*)&As[e0] = *(const u16x8*)&A[(long long)(m0 + r0r) * K + kt + c0c];
    *(u16x8*)&Bs[e0] = *(const u16x8*)&BT[(long long)(n0 + r0r) * K + kt + c0c];
    *(u16x8*)&Bs[e1] = *(const u16x8*)&BT[(long long)(n0 + r1r) * K + kt + c1c];
    __syncthreads();
    bf16x8 af[2], bfv[4];
#pragma unroll
    for (int i = 0; i < 2; i++) af[i] = *(const bf16x8*)&As[(mw + i * 16 + fr) * 32 + fg * 8];
#pragma unroll
    for (int j = 0; j < 4; j++) bfv[j] = *(const bf16x8*)&Bs[(nw + j * 16 + fr) * 32 + fg * 8];
#pragma unroll
    for (int i = 0; i < 2; i++)
#pragma unroll
      for (int j = 0; j < 4; j++)
        acc[i][j] = __builtin_amdgcn_mfma_f32_16x16x32_bf16(af[i], bfv[j], acc[i][j], 0, 0, 0);
    __syncthreads();
  }
#pragma unroll
  for (int i = 0; i < 2; i++)
#pragma unroll
    for (int j = 0; j < 4; j++) {
      int mloc = mw + i * 16 + fg * 4;
      int n = n0 + nw + j * 16 + fr;
      float bvl;
      if constexpr (MODE == 5) {
        int seg = n >> 9, nn = n & 511;
        bvl = (seg == 0 ? bias : seg == 1 ? biasK : biasV)[nn];
      } else {
        bvl = bias ? bias[n] : 0.f;
      }
#pragma unroll
      for (int r = 0; r < 4; r++) {
        int m = m0 + mloc + r;
        float v = acc[i][j][r] * scale + bvl;
        if constexpr (MODE == 0) {
          outF[(long long)m * N + n] = v;
        } else if constexpr (MODE == 4) {
          outF[(long long)m * N + n] = v;
          outB[(long long)m * N + n] = f2b(v);
        } else if constexpr (MODE == 5) {
          int seg = n >> 9, nn = n & 511;
          if (seg == 0) v *= 0.125f;  // prescale Q by 1/8 (exact power of 2)
          u16 val = f2b(v);
          if (seg == 2) {
            outBV[((long long)((m >> 11) * NH + (nn >> 6)) * 64 + (nn & 63)) * S_LEN + (m & 2047)] = val;
          } else {
            long long qkidx = (long long)((m >> 11) * NH + (nn >> 6)) * (S_LEN * 64) +
                              (long long)(m & 2047) * 64 + (nn & 63);
            if (seg == 0) outB[qkidx] = val;
            else outBK[qkidx] = val;
          }
        }
      }
    }
}

// ---------------- merged kernel: QK scores -> exact top-k threshold -> masked softmax PV ----------------
// grid (128, 16): 16 query rows per block, one (b,h). block = 1024 (16 waves).
// Phase 1: swapped-operand QK^T (lane holds 1 q-row x 4 consecutive k-cols) -> raw bf16 score
//          bits to LDS via ds_write_b64.
// Phase 2: wave wv selects row wv's threshold: unpack to 32 float regs, seeded binary search
//          in 16-bit monotone-code space with scalar midpoints, ballot+popcount counting.
// Phase 3: wave wv PVs its 128-col K-slice reading raw bf16 scores (decode = 1 shift).
// Phase 4: cross-wave reduce of partial O (dead key region) and Z.
__global__ __launch_bounds__(1024, 8) void score_pv(
    const u16* __restrict__ Qb, const u16* __restrict__ Kb, const u16* __restrict__ VTb,
    u16* __restrict__ aoB) {
  __shared__ u16 Qs[16 * 64];                  // 2 KB swizzled
  __shared__ __align__(16) u16 Ss[16 * 2048];  // 64 KB raw bf16 scores; reused as fp32 partial-O
  __shared__ float thrS[16];
  __shared__ float mS[16];
  __shared__ float zS[16 * 16];
  int bh = blockIdx.y, m0 = blockIdx.x * 16, t = threadIdx.x;
  int lane = t & 63, wv = t >> 6, fr = lane & 15, fg = lane >> 4;
  const u16* Qg = Qb + ((long long)bh * S_LEN + m0) * 64;
  const u16* Kg = Kb + (long long)bh * S_LEN * 64;
  const u16* Vg = VTb + (long long)bh * 64 * S_LEN;
  if (t < 128) {
    int row = t >> 3, cc = t & 7;
    *(u16x8*)&Qs[row * 64 + ((cc ^ (row & 7)) * 8)] = *(const u16x8*)&Qg[row * 64 + cc * 8];
  }
  __syncthreads();
  bf16x8 aq[2];
#pragma unroll
  for (int ks = 0; ks < 2; ks++)
    aq[ks] = *(const bf16x8*)&Qs[fr * 64 + (((fg + 4 * ks) ^ (fr & 7)) * 8)];

  // ---- phase 1: wave wv computes cols [wv*128, wv*128+127] ----
  // mfma(K,Q): lane (fr,fg) reg r -> score[q=fr][k=col0+fg*4+r] : 4 consecutive cols, 1 b64 write
#pragma unroll 4
  for (int tt = 0; tt < 8; tt++) {
    int col0 = wv * 128 + tt * 16;
    f32x4 acc = {};
#pragma unroll
    for (int ks = 0; ks < 2; ks++) {
      bf16x8 bk = *(const bf16x8*)&Kg[(long long)(col0 + fr) * 64 + ks * 32 + fg * 8];
      acc = __builtin_amdgcn_mfma_f32_16x16x32_bf16(bk, aq[ks], acc, 0, 0, 0);
    }
    uint2 w;
    w.x = f2b_fast(acc[0]) | (f2b_fast(acc[1]) << 16);
    w.y = f2b_fast(acc[2]) | (f2b_fast(acc[3]) << 16);
    int row = fr, col = col0 + fg * 4;
    *(uint2*)&Ss[row * 2048 + (col ^ ((row & 15) << 3))] = w;
  }
  __syncthreads();

  // ---- phase 2: wave wv selects threshold for row wv ----
  {
    int rr = wv;
    const uint2* cu2 = (const uint2*)&Ss[rr * 2048];
    float kf[32];
#pragma unroll
    for (int j = 0; j < 8; j++) {
      uint2 w = cu2[lane + 64 * j];
      kf[4 * j + 0] = __uint_as_float(w.x << 16);
      kf[4 * j + 1] = __uint_as_float(w.x & 0xFFFF0000u);
      kf[4 * j + 2] = __uint_as_float(w.y << 16);
      kf[4 * j + 3] = __uint_as_float(w.y & 0xFFFF0000u);
    }
    float mxf = kf[0];
#pragma unroll
    for (int j = 1; j < 32; j++) mxf = fmaxf(mxf, kf[j]);
#pragma unroll
    for (int o = 1; o < 64; o <<= 1)
      mxf = fmaxf(mxf, __uint_as_float((unsigned)__shfl_xor((int)__float_as_uint(mxf), o)));
    unsigned mxi = fkmap(mxf);
    // seeded exact binary search: probe mx-384 first (codes), fall back to [0, lo0-1] if short
    unsigned lo, hi;
    unsigned lo0 = mxi > 384u ? mxi - 384u : 0u;
    {
      float pf = kunmap(lo0);
      int c = 0;
#pragma unroll
      for (int j = 0; j < 32; j++) c += (int)__popcll(__ballot(kf[j] >= pf));
      if (c >= TOPK) { lo = lo0; hi = mxi; }
      else { lo = 0u; hi = lo0 - 1u; }
    }
    while (lo < hi) {
      unsigned mid = (lo + hi + 1u) >> 1;
      float midf = kunmap(mid);
      int c = 0;
#pragma unroll
      for (int j = 0; j < 32; j++) c += (int)__popcll(__ballot(kf[j] >= midf));
      if (c >= TOPK) lo = mid; else hi = mid - 1u;
    }
    if (lane == 0) {
      thrS[rr] = kunmap(lo);
      mS[rr] = mxf;
    }
  }
  __syncthreads();

  // ---- phase 3: wave wv PVs its K-slice [wv*128, wv*128+127] from stored bf16 scores ----
  float thrF = thrS[fr];
  float myM = mS[fr];
  float zpart = 0.f;
  f32x4 acc_o[4] = {};
#pragma unroll 2
  for (int step = 0; step < 4; step++) {
    int k0 = wv * 128 + step * 32;
    u16x8 kk = *(const u16x8*)&Ss[fr * 2048 + ((k0 + fg * 8) ^ ((fr & 15) << 3))];
    unsigned wp[4];
#pragma unroll
    for (int e2 = 0; e2 < 4; e2++) {
      float s0 = __uint_as_float((unsigned)kk[2 * e2] << 16);
      float s1 = __uint_as_float((unsigned)kk[2 * e2 + 1] << 16);
      float p0 = (s0 >= thrF) ? __expf(s0 - myM) : 0.f;
      float p1 = (s1 >= thrF) ? __expf(s1 - myM) : 0.f;
      zpart += p0 + p1;
      wp[e2] = f2b_fast(p0) | (f2b_fast(p1) << 16);
    }
    bf16x8 pa = *(bf16x8*)&wp;
#pragma unroll
    for (int j = 0; j < 4; j++) {
      bf16x8 bv = *(const bf16x8*)&Vg[(long long)(j * 16 + fr) * 2048 + k0 + fg * 8];
      acc_o[j] = __builtin_amdgcn_mfma_f32_16x16x32_bf16(pa, bv, acc_o[j], 0, 0, 0);
    }
  }
  zpart += __shfl_xor(zpart, 16);
  zpart += __shfl_xor(zpart, 32);
  __syncthreads();  // all waves done reading keys

  // ---- phase 4: partials into dead key region (fg-swizzled), cross-wave reduce, output ----
  float* Of = (float*)Ss;  // 16 waves x [16][64] fp32 = 64 KB
#pragma unroll
  for (int j = 0; j < 4; j++)
#pragma unroll
    for (int r = 0; r < 4; r++) {
      int row = fg * 4 + r, col = j * 16 + fr;
      Of[wv * 1024 + row * 64 + (col ^ ((row >> 2) << 3))] = acc_o[j][r];
    }
  if (fg == 0) zS[wv * 16 + fr] = zpart;
  __syncthreads();
  long long ob = (long long)(bh >> 3) * S_LEN * DMODEL + (bh & 7) * 64;
  {
    int row = t >> 6, dk = t & 63;
    int sw = dk ^ ((row >> 2) << 3);
    float s = 0.f;
#pragma unroll
    for (int w = 0; w < 16; w++) s += Of[w * 1024 + row * 64 + sw];
    float z = 0.f;
#pragma unroll
    for (int w = 0; w < 16; w++) z += zS[w * 16 + row];
    aoB[ob + (long long)(m0 + row) * DMODEL + dk] = f2b(s / z);
  }
}

// ---------------- residual + LayerNorm ----------------
__global__ __launch_bounds__(256) void resid_ln(const float* __restrict__ h, const float* __restrict__ fco,
                                                const float* __restrict__ g, const float* __restrict__ b,
                                                float* __restrict__ hout, u16* __restrict__ hbout) {
  __shared__ float red[4];
  int row = blockIdx.x;
  int t = threadIdx.x;
  long long base = (long long)row * 512;
  float v0 = h[base + t] + fco[base + t];
  float v1 = h[base + t + 256] + fco[base + t + 256];
  float s = v0 + v1;
#pragma unroll
  for (int o = 32; o > 0; o >>= 1) s += __shfl_down(s, o);
  if ((t & 63) == 0) red[t >> 6] = s;
  __syncthreads();
  float mu = (red[0] + red[1] + red[2] + red[3]) * (1.f / 512.f);
  float d0 = v0 - mu, d1 = v1 - mu;
  float q = d0 * d0 + d1 * d1;
#pragma unroll
  for (int o = 32; o > 0; o >>= 1) q += __shfl_down(q, o);
  __syncthreads();
  if ((t & 63) == 0) red[t >> 6] = q;
  __syncthreads();
  float var = (red[0] + red[1] + red[2] + red[3]) * (1.f / 512.f);
  float rs = rsqrtf(var + 1e-5f);
  float y0 = d0 * rs * g[t] + b[t];
  float y1 = d1 * rs * g[t + 256] + b[t + 256];
  hout[base + t] = y0;
  hout[base + t + 256] = y1;
  hbout[base + t] = f2b(y0);
  hbout[base + t + 256] = f2b(y1);
}

// ---------------- decoder ----------------
__global__ void decoder_k(const float* __restrict__ h, const float* __restrict__ W,
                          const float* __restrict__ bias, float* __restrict__ out) {
  int t = threadIdx.x;
  int b = t >> 6, j = t & 63;
  const float* hr = h + ((long long)b * S_LEN + (S_LEN - 1)) * DMODEL;
  float s = 0.f;
  for (int d = 0; d < DMODEL; d++) s += hr[d] * W[(long long)d * 64 + j];
  out[t] = s + bias[j];
}

extern "C" void kernel_launch(void* const* d_in, const int* in_sizes, int n_in,
                              void* d_out, int out_size, void* d_ws, size_t ws_size,
                              hipStream_t stream) {
  const float* x = (const float*)d_in[0];
  const float* enc_W = (const float*)d_in[1];
  const float* enc_b = (const float*)d_in[2];
  const float* Wq = (const float*)d_in[3];
  const float* bq = (const float*)d_in[4];
  const float* Wk = (const float*)d_in[5];
  const float* bk = (const float*)d_in[6];
  const float* Wv = (const float*)d_in[7];
  const float* bv = (const float*)d_in[8];
  const float* fcW = (const float*)d_in[9];
  const float* fcb = (const float*)d_in[10];
  const float* ln_g = (const float*)d_in[11];
  const float* ln_b = (const float*)d_in[12];
  const float* dec_W = (const float*)d_in[13];
  const float* dec_b = (const float*)d_in[14];

  char* p = (char*)d_ws;
  auto alloc = [&](size_t bytes) {
    char* r = p;
    p += (bytes + 255) & ~(size_t)255;
    return r;
  };
  const size_t BS = 2 * (size_t)S_LEN;
  u16* encWT = (u16*)alloc(512 * 64 * 2);
  u16* xbf = (u16*)alloc(BS * 64 * 2);
  float* hF = (float*)alloc(BS * 512 * 4);
  u16* hB = (u16*)alloc(BS * 512 * 2);
  u16* WqT = (u16*)alloc(512 * 512 * 2);  // WqT/WkT/WvT contiguous => one [1536][512] B matrix
  u16* WkT = (u16*)alloc(512 * 512 * 2);
  u16* WvT = (u16*)alloc(512 * 512 * 2);
  u16* fcWT = (u16*)alloc(512 * 512 * 2);
  u16* Qb = (u16*)alloc((size_t)16 * 2048 * 64 * 2);
  u16* Kb = (u16*)alloc((size_t)16 * 2048 * 64 * 2);
  u16* VTb = (u16*)alloc((size_t)16 * 2048 * 64 * 2);
  u16* aoB = (u16*)alloc(BS * 512 * 2);
  float* fcO = (float*)Qb;  // alias: Qb+Kb (8 MB) dead after score_pv

  transpose_w<<<dim3(16, 2), 256, 0, stream>>>(enc_W, encWT, 64, 512);
  conv_b<<<(int)(BS * 64 / 256), 256, 0, stream>>>(x, xbf, (int)(BS * 64));
  gemm_bt<4><<<dim3(4, 64), 256, 0, stream>>>(xbf, encWT, enc_b, nullptr, nullptr,
                                              hF, hB, nullptr, nullptr, 4096, 512, 64, 1.f);

  for (int l = 0; l < 2; l++) {
    transpose_w4<<<dim3(16, 16, 4), 256, 0, stream>>>(
        Wq + (size_t)l * 512 * 512, Wk + (size_t)l * 512 * 512,
        Wv + (size_t)l * 512 * 512, fcW + (size_t)l * 512 * 512,
        WqT, WkT, WvT, fcWT);
    gemm_bt<5><<<dim3(12, 64), 256, 0, stream>>>(hB, WqT, bq + l * 512, bk + l * 512, bv + l * 512,
                                                 nullptr, Qb, Kb, VTb, 4096, 1536, 512, 1.f);
    score_pv<<<dim3(128, 16), 1024, 0, stream>>>(Qb, Kb, VTb, aoB);
    gemm_bt<0><<<dim3(4, 64), 256, 0, stream>>>(aoB, fcWT, fcb + l * 512, nullptr, nullptr,
                                                fcO, nullptr, nullptr, nullptr, 4096, 512, 512, 1.f);
    resid_ln<<<4096, 256, 0, stream>>>(hF, fcO, ln_g + l * 512, ln_b + l * 512, hF, hB);
  }
  decoder_k<<<1, 128, 0, stream>>>(hF, dec_W, dec_b, (float*)d_out);
}